// Round 6
// baseline (167.292 us; speedup 1.0000x reference)
//
#include <hip/hip_runtime.h>

// GCN link-prediction forward: 2× GCNConv (128->128 relu, 128->64) on
// N=50000 nodes, E=800000 random edges. fp32 compute, int8 messages.
//
// Algebra: with dis[n] = rsqrt(indeg[n]+1),
//   conv(x)[c] = ( sum_{r->c} h[r]*dis[r] + h[c]*dis[c] ) * dis[c] + b,
//   h = x@W (unscaled). Messages stored int8 (per-row scale, biased +128;
//   exact -128 correction via K = sum of scales).
//
// R2..R9: 2737 -> 169 us (CSR gather, MFMA, fusion, bucketed sort).
// R10: src-sorted gather: +1% -- locality hypothesis falsified.
// R11: layer-1 messages int8 (169 -> 161 us).
// R12: layer-2 int8 restructure REGRESSED (parallelism cut). REVERTED.
// R14: layer-2 int8, UNCHANGED L=8 decomposition: neutral; gather2
//      LATENCY-bound, not traffic-bound. KEPT.
// R15: W1/W2 pre-packed bf16 fragment-major: 158.8.
// R16: gathers de-shuffled (direct 16B ushort8 idx loads, 8-padded CSR
//      starts): 152.1 us. BEST.
// R17: cooperative fusion: 301 us. grid.sync ~100us+/sync on 8 XCDs.
//      REVERTED. But phases themselves cheap (VALU 1%, HBM 2%).
// R18: dummy-pad + x2 unroll gathers: 156.1 (+22% wasted pad loads, VGPR
//      pressure). REVERTED to R16 gather loops.
// R19: 5 -> 4 dispatches, no grid sync: k_pack eliminated (GEMM1
//      self-converts W1 per R13; w2f packed by tail blocks of the fused
//      dispatch); partition uses fixed per-(block,bucket) sub-windows
//      (SUBCAP=80 = mean 32 + 8.6 sigma) -> no global cursor atomics, no
//      memset, poison-safe. k_csr streams (chunk,pos) validity via histg.

typedef unsigned int u32;
typedef unsigned short ushort;
typedef __attribute__((ext_vector_type(8))) short short8;
typedef __attribute__((ext_vector_type(8))) unsigned short us8;
typedef __attribute__((ext_vector_type(4))) float floatx4;

static inline int cdiv_l(long a, int b) { return (int)((a + b - 1) / b); }

constexpr int NPB    = 512;    // nodes per bucket (2^9)
constexpr int EPB    = 4096;   // edges per partition block
constexpr int MAXB   = 128;    // max buckets (N <= 65536)
constexpr int SUBCAP = 80;     // per-(block,bucket) ebuf slots; mean 32,
                               // sigma 5.66 -> 80 = +8.6 sigma (safe)
constexpr int CAPW   = 16384;  // per-bucket csr window (padded worst ~12k)

__device__ __forceinline__ u32 pack_bf16(float a, float b) {
  union { float f; u32 i; } ua, ub;
  ua.f = a; ub.f = b;
  u32 x = (ua.i + 0x7fffu + ((ua.i >> 16) & 1u)) >> 16;           // rne, low
  u32 y = (ub.i + 0x7fffu + ((ub.i >> 16) & 1u)) & 0xffff0000u;   // rne, high
  return x | y;
}

__device__ __forceinline__ short bf16r(float f) {
  union { float f; u32 i; } u; u.f = f;
  return (short)((u.i + 0x7fffu + ((u.i >> 16) & 1u)) >> 16);     // rne
}

// int8 dequant-accumulate: 8 biased uint8 -> acc += (float)q * sd
// (the -128 bias is corrected once per node via K = sum of sd).
__device__ __forceinline__ void dq8(float* a, uint2 v, float sd) {
  a[0] += (float)(v.x & 255u) * sd;
  a[1] += (float)((v.x >> 8) & 255u) * sd;
  a[2] += (float)((v.x >> 16) & 255u) * sd;
  a[3] += (float)(v.x >> 24) * sd;
  a[4] += (float)(v.y & 255u) * sd;
  a[5] += (float)((v.y >> 8) & 255u) * sd;
  a[6] += (float)((v.y >> 16) & 255u) * sd;
  a[7] += (float)(v.y >> 24) * sd;
}

// ---- dispatch 1 (fused front): blocks [0,NBE): edge partition into fixed
// ---- sub-windows; [NBE,NBE+G1): GEMM1 (self-converted W1) + int8;
// ---- [NBE+G1,+4): pack W2 fragments for k_gg. All independent.
__global__ __launch_bounds__(256) void k_front(
    const int* __restrict__ ei, u32* __restrict__ ebuf,
    int* __restrict__ histg, int E, int NBE, int G1,
    const float* __restrict__ x, const float* __restrict__ W1,
    const float* __restrict__ W2, u32* __restrict__ w2f,
    u32* __restrict__ h8, float* __restrict__ scale, int N) {
  __shared__ float eb[4][16 * 133];   // 34 KB union workspace
  const int tid = threadIdx.x;
  const int blk = blockIdx.x;

  if (blk >= NBE + G1) {
    // ===== pack W2: 128x64 -> 1024 slots (4 blocks x 256) =====
    const int s = (blk - NBE - G1) * 256 + tid;
    const int lane = s & 63, frag = s >> 6;
    const int kc = frag >> 2, cb = frag & 3;
    const float* src =
        W2 + (long)(kc * 32 + (lane >> 4) * 8) * 64 + cb * 16 + (lane & 15);
    u32 o[4];
#pragma unroll
    for (int p = 0; p < 4; ++p)
      o[p] = pack_bf16(src[(2 * p) * 64], src[(2 * p + 1) * 64]);
    *(uint4*)(w2f + (long)s * 4) = make_uint4(o[0], o[1], o[2], o[3]);
    return;
  }

  if (blk < NBE) {
    // ===== edge partition into fixed sub-windows (no global atomics) =====
    u32* ecache = (u32*)&eb[0][0];          // 4096 u32 = 16 KB
    int* hist   = (int*)&eb[2][0];          // MAXB counts
    int* curs   = hist + MAXB;              // MAXB local cursors
    const int* ecol = ei + E;
    if (tid < MAXB) { hist[tid] = 0; curs[tid] = 0; }
    __syncthreads();
    const int base = blk * EPB;
#pragma unroll
    for (int j = 0; j < EPB / 256; ++j) {
      int e = base + j * 256 + tid;
      u32 pk = 0xffffffffu;
      if (e < E) {
        u32 r = (u32)ei[e];
        u32 c = (u32)ecol[e];
        pk = r | (c << 16);
        atomicAdd(hist + (c >> 9), 1);
      }
      ecache[j * 256 + tid] = pk;
    }
    __syncthreads();
    if (tid < MAXB) histg[blk * MAXB + tid] = min(hist[tid], SUBCAP);
    __syncthreads();
#pragma unroll
    for (int j = 0; j < EPB / 256; ++j) {
      u32 pk = ecache[j * 256 + tid];
      if (pk != 0xffffffffu) {
        u32 c = pk >> 16;
        int b = c >> 9;
        int p = atomicAdd(curs + b, 1);
        if (p < SUBCAP)   // overflow guard (8.6 sigma)
          ebuf[(long)b * (NBE * SUBCAP) + blk * SUBCAP + p] =
              (pk & 0xffffu) | ((c & (NPB - 1)) << 16);
      }
    }
    return;
  }

  // ===== MFMA GEMM1: h8[row,:] = int8(x[row,:] @ W1), K=M=128 =====
  // W1 converted in-lane (R13 pattern): strided f32 loads + bf16r.
  constexpr int K = 128, M = 128, NC = 8, LROW = 133;
  const int w = tid >> 6, lane = tid & 63;
  const int quad = lane >> 4, n16 = lane & 15;
  const int row0 = ((blk - NBE) * 4 + w) * 16;

  floatx4 acc[NC];
#pragma unroll
  for (int c = 0; c < NC; ++c) acc[c] = {0.f, 0.f, 0.f, 0.f};

  const int am = row0 + n16;
  const bool av = am < N;
  const float* arow = x + (long)am * K;

#pragma unroll
  for (int kc = 0; kc < 4; ++kc) {
    const int kb = kc * 32 + quad * 8;
    float4 a0 = make_float4(0.f, 0.f, 0.f, 0.f);
    float4 a1 = make_float4(0.f, 0.f, 0.f, 0.f);
    if (av) {
      a0 = *(const float4*)(arow + kb);
      a1 = *(const float4*)(arow + kb + 4);
    }
    short8 af;
    af[0] = bf16r(a0.x); af[1] = bf16r(a0.y); af[2] = bf16r(a0.z); af[3] = bf16r(a0.w);
    af[4] = bf16r(a1.x); af[5] = bf16r(a1.y); af[6] = bf16r(a1.z); af[7] = bf16r(a1.w);
    const float* wbase = W1 + (long)kb * M + n16;
#pragma unroll
    for (int c = 0; c < NC; ++c) {
      const float* wp = wbase + c * 16;
      short8 bf;
      bf[0] = bf16r(wp[0 * M]); bf[1] = bf16r(wp[1 * M]);
      bf[2] = bf16r(wp[2 * M]); bf[3] = bf16r(wp[3 * M]);
      bf[4] = bf16r(wp[4 * M]); bf[5] = bf16r(wp[5 * M]);
      bf[6] = bf16r(wp[6 * M]); bf[7] = bf16r(wp[7 * M]);
      acc[c] = __builtin_amdgcn_mfma_f32_16x16x32_bf16(af, bf, acc[c], 0, 0, 0);
    }
  }

  float* ep = eb[w];
#pragma unroll
  for (int c = 0; c < NC; ++c)
#pragma unroll
    for (int r = 0; r < 4; ++r)
      ep[(quad * 4 + r) * LROW + c * 16 + n16] = acc[c][r];
  __syncthreads();

  // int8 quantize: lane -> row rr = lane>>2, col segment seg*32..+31
  const int rr = lane >> 2, seg = lane & 3;
  const float* rowp = ep + rr * LROW + seg * 32;
  float m = 0.f;
#pragma unroll
  for (int c = 0; c < 32; ++c) m = fmaxf(m, fabsf(rowp[c]));
  m = fmaxf(m, __shfl_xor(m, 1, 4));
  m = fmaxf(m, __shfl_xor(m, 2, 4));
  const float inv = (m > 0.f) ? 127.f / m : 0.f;
  const float s = m / 127.f;
  u32 q[8];
#pragma unroll
  for (int wd = 0; wd < 8; ++wd) {
    u32 b0 = (u32)((int)rintf(rowp[wd * 4 + 0] * inv) + 128);
    u32 b1 = (u32)((int)rintf(rowp[wd * 4 + 1] * inv) + 128);
    u32 b2 = (u32)((int)rintf(rowp[wd * 4 + 2] * inv) + 128);
    u32 b3 = (u32)((int)rintf(rowp[wd * 4 + 3] * inv) + 128);
    q[wd] = (b0 & 255u) | ((b1 & 255u) << 8) | ((b2 & 255u) << 16) | (b3 << 24);
  }
  const int rg = row0 + rr;
  if (rg < N) {
    uint4* dst = (uint4*)(h8 + (long)rg * 32 + seg * 8);
    dst[0] = make_uint4(q[0], q[1], q[2], q[3]);
    dst[1] = make_uint4(q[4], q[5], q[6], q[7]);
    if (seg == 0) scale[rg] = s;
  }
}

// ---- dispatch 2: per-bucket CSR finalize from sub-windows + sd fold;
// ---- node list starts padded to 8 (aligned us8 index loads). ----
__global__ __launch_bounds__(NPB) void k_csr(const u32* __restrict__ ebuf,
                                             const int* __restrict__ histg,
                                             const float* __restrict__ scale,
                                             int* __restrict__ off,
                                             int* __restrict__ deg,
                                             float* __restrict__ dis,
                                             float* __restrict__ sd,
                                             ushort* __restrict__ csr,
                                             int NBE, int N) {
  __shared__ int cnt[NPB];
  __shared__ int curl[NPB];
  __shared__ int wsum[NPB / 64];
  const int tid = threadIdx.x;
  const int b = blockIdx.x;
  const int TOT = NBE * SUBCAP;
  const long ebase = (long)b * TOT;
  cnt[tid] = 0;
  __syncthreads();
  // count pass over valid (chunk,pos) slots
  for (int i = tid; i < TOT; i += NPB) {
    const int chunk = i / SUBCAP;
    const int pos = i - chunk * SUBCAP;
    if (pos < histg[chunk * MAXB + b])
      atomicAdd(cnt + (ebuf[ebase + i] >> 16), 1);
  }
  __syncthreads();
  const int lane = tid & 63, w = tid >> 6;
  const int v = cnt[tid];
  const int vp = (v + 7) & ~7;    // padded length (8-aligned starts)
  int incl = vp;
#pragma unroll
  for (int d = 1; d < 64; d <<= 1) {
    int x = __shfl_up(incl, d, 64);
    if (lane >= d) incl += x;
  }
  if (lane == 63) wsum[w] = incl;
  __syncthreads();
  if (w == 0 && lane < NPB / 64) {
    int sv = wsum[lane];
#pragma unroll
    for (int d = 1; d < NPB / 64; d <<= 1) {
      int x = __shfl_up(sv, d, 64);
      if (lane >= d) sv += x;
    }
    wsum[lane] = sv;
  }
  __syncthreads();
  const int excl = ((w > 0) ? wsum[w - 1] : 0) + incl - vp;
  const int node = b * NPB + tid;
  if (node < N) {
    float dv = rsqrtf((float)v + 1.0f);
    off[node] = b * CAPW + excl;
    deg[node] = v;
    dis[node] = dv;
    sd[node] = scale[node] * dv;
  }
  curl[tid] = excl;
  __syncthreads();
  // scatter pass
  ushort* cw = csr + (long)b * CAPW;
  for (int i = tid; i < TOT; i += NPB) {
    const int chunk = i / SUBCAP;
    const int pos = i - chunk * SUBCAP;
    if (pos < histg[chunk * MAXB + b]) {
      u32 pk = ebuf[ebase + i];
      int p = atomicAdd(curl + (pk >> 16), 1);
      cw[p] = (ushort)(pk & 0xffffu);
    }
  }
}

// ---- dispatch 3: fused gather1 (int8 msgs, direct idx loads) + relu +
// ---- GEMM2; epilogue quantizes h2 to int8 (per-row scale s2). ----
__global__ __launch_bounds__(256) void k_gg(
    const uint2* __restrict__ h8, const int* __restrict__ off,
    const int* __restrict__ deg, const ushort* __restrict__ csr,
    const float* __restrict__ dis, const float* __restrict__ sd,
    const float* __restrict__ b1, const u32* __restrict__ w2f,
    u32* __restrict__ h2, float* __restrict__ s2, int N) {
  constexpr int LG = 65;   // u32 words per g row (64 + pad)
  constexpr int LC = 66;   // f32 words per C row (64 + pad)
  __shared__ u32 lg[16 * LG];
  __shared__ float cb[16 * LC];
  const int tid = threadIdx.x;
  const int r = tid >> 4;          // local node 0..15
  const int lf = tid & 15;         // lane within 16-group (8-byte chunk)
  const int row0 = blockIdx.x * 16;
  const int n = row0 + r;

  // ---- phase 1: int8 gather (rows = 128B = 2 lines) ----
  u32 gw[4] = {0, 0, 0, 0};
  if (n < N) {
    const int s = off[n], e = s + deg[n];
    const float dn = dis[n];
    float acc[8] = {};
    float K = 0.f;
    {
      float sn = sd[n];
      dq8(acc, h8[(long)n * 16 + lf], sn);  // self-loop
      K += sn;
    }
    int j = s;
    for (; j + 8 <= e; j += 8) {
      us8 ev = *(const us8*)(csr + j);   // 16B aligned broadcast load
      const int i0 = ev[0], i1 = ev[1], i2 = ev[2], i3 = ev[3];
      const int i4 = ev[4], i5 = ev[5], i6 = ev[6], i7 = ev[7];
      const float d0 = sd[i0], d1 = sd[i1], d2 = sd[i2], d3 = sd[i3];
      const float d4 = sd[i4], d5 = sd[i5], d6 = sd[i6], d7 = sd[i7];
      uint2 v0 = h8[(long)i0 * 16 + lf];
      uint2 v1 = h8[(long)i1 * 16 + lf];
      uint2 v2 = h8[(long)i2 * 16 + lf];
      uint2 v3 = h8[(long)i3 * 16 + lf];
      uint2 v4 = h8[(long)i4 * 16 + lf];
      uint2 v5 = h8[(long)i5 * 16 + lf];
      uint2 v6 = h8[(long)i6 * 16 + lf];
      uint2 v7 = h8[(long)i7 * 16 + lf];
      dq8(acc, v0, d0); dq8(acc, v1, d1); dq8(acc, v2, d2); dq8(acc, v3, d3);
      dq8(acc, v4, d4); dq8(acc, v5, d5); dq8(acc, v6, d6); dq8(acc, v7, d7);
      K += ((d0 + d1) + (d2 + d3)) + ((d4 + d5) + (d6 + d7));
    }
    if (j < e) {
      us8 ev = *(const us8*)(csr + j);
#pragma unroll
      for (int t = 0; t < 8; ++t) {
        if (j + t < e) {
          const int it = ev[t];
          const float dt = sd[it];
          dq8(acc, h8[(long)it * 16 + lf], dt);
          K += dt;
        }
      }
    }
    const int f8 = lf * 8;
    const float4 bv0 = *(const float4*)(b1 + f8);
    const float4 bv1 = *(const float4*)(b1 + f8 + 4);
    const float bb[8] = {bv0.x, bv0.y, bv0.z, bv0.w, bv1.x, bv1.y, bv1.z, bv1.w};
    const float kc = 128.f * K;
#pragma unroll
    for (int q = 0; q < 8; ++q)
      acc[q] = fmaxf((acc[q] - kc) * dn + bb[q], 0.f);
#pragma unroll
    for (int q = 0; q < 4; ++q)
      gw[q] = pack_bf16(acc[2 * q], acc[2 * q + 1]);
  }
#pragma unroll
  for (int q = 0; q < 4; ++q) lg[r * LG + lf * 4 + q] = gw[q];
  __syncthreads();

  // ---- phase 2: 16x128x64 MFMA; wave w owns cols w*16..w*16+15 ----
  const int w = tid >> 6, lane = tid & 63;
  const int quad = lane >> 4, n16 = lane & 15;
  floatx4 acc4 = {0.f, 0.f, 0.f, 0.f};
#pragma unroll
  for (int kc = 0; kc < 4; ++kc) {
    const int kb = kc * 32 + quad * 8;
    const u32* ap = &lg[n16 * LG + (kb >> 1)];
    u32 aw[4] = {ap[0], ap[1], ap[2], ap[3]};
    short8 af = *(short8*)aw;
    short8 bf = ((const short8*)w2f)[(kc * 4 + w) * 64 + lane];
    acc4 = __builtin_amdgcn_mfma_f32_16x16x32_bf16(af, bf, acc4, 0, 0, 0);
  }
  float dd[4];
#pragma unroll
  for (int r4 = 0; r4 < 4; ++r4) {
    int rg = row0 + quad * 4 + r4;
    dd[r4] = (rg < N) ? dis[rg] : 0.f;
  }
#pragma unroll
  for (int r4 = 0; r4 < 4; ++r4)
    cb[(quad * 4 + r4) * LC + w * 16 + n16] = acc4[r4] * dd[r4];
  __syncthreads();

  // ---- int8 quantize h2 rows: 16 lanes per row, 4 cols each ----
  const int rr2 = tid >> 4, lf2 = tid & 15;
  const float* rp = cb + rr2 * LC + lf2 * 4;
  float mx = fmaxf(fmaxf(fabsf(rp[0]), fabsf(rp[1])),
                   fmaxf(fabsf(rp[2]), fabsf(rp[3])));
  mx = fmaxf(mx, __shfl_xor(mx, 1, 16));
  mx = fmaxf(mx, __shfl_xor(mx, 2, 16));
  mx = fmaxf(mx, __shfl_xor(mx, 4, 16));
  mx = fmaxf(mx, __shfl_xor(mx, 8, 16));
  const float inv2 = (mx > 0.f) ? 127.f / mx : 0.f;
  const int rg2 = row0 + rr2;
  if (rg2 < N) {
    u32 q0 = (u32)((int)rintf(rp[0] * inv2) + 128);
    u32 q1 = (u32)((int)rintf(rp[1] * inv2) + 128);
    u32 q2 = (u32)((int)rintf(rp[2] * inv2) + 128);
    u32 q3 = (u32)((int)rintf(rp[3] * inv2) + 128);
    h2[(long)rg2 * 16 + lf2] =
        (q0 & 255u) | ((q1 & 255u) << 8) | ((q2 & 255u) << 16) | (q3 << 24);
    if (lf2 == 0) s2[rg2] = mx / 127.f;
  }
}

// ---- dispatch 4: layer-2 gather (int8 h2, direct idx loads) + bias ----
__global__ __launch_bounds__(256) void k_gather2(
    const uint2* __restrict__ hs, const int* __restrict__ off,
    const int* __restrict__ deg, const ushort* __restrict__ csr,
    const float* __restrict__ dis, const float* __restrict__ sc2,
    const float* __restrict__ bias, float* __restrict__ out, int N) {
  constexpr int L = 8;  // lanes per node
  const int local = threadIdx.x / L;
  const int lf = threadIdx.x % L;
  const int n = blockIdx.x * (256 / L) + local;
  if (n >= N) return;
  const int s = off[n], e = s + deg[n];
  float acc[8] = {};
  float K = 0.f;
  {
    float t0 = sc2[n];
    dq8(acc, hs[(long)n * L + lf], t0);  // self-loop
    K += t0;
  }
  int j = s;
  for (; j + 8 <= e; j += 8) {
    us8 ev = *(const us8*)(csr + j);   // 16B aligned broadcast load
    const int i0 = ev[0], i1 = ev[1], i2 = ev[2], i3 = ev[3];
    const int i4 = ev[4], i5 = ev[5], i6 = ev[6], i7 = ev[7];
    const float d0 = sc2[i0], d1 = sc2[i1], d2 = sc2[i2], d3 = sc2[i3];
    const float d4 = sc2[i4], d5 = sc2[i5], d6 = sc2[i6], d7 = sc2[i7];
    uint2 v0 = hs[(long)i0 * L + lf];
    uint2 v1 = hs[(long)i1 * L + lf];
    uint2 v2 = hs[(long)i2 * L + lf];
    uint2 v3 = hs[(long)i3 * L + lf];
    uint2 v4 = hs[(long)i4 * L + lf];
    uint2 v5 = hs[(long)i5 * L + lf];
    uint2 v6 = hs[(long)i6 * L + lf];
    uint2 v7 = hs[(long)i7 * L + lf];
    dq8(acc, v0, d0); dq8(acc, v1, d1); dq8(acc, v2, d2); dq8(acc, v3, d3);
    dq8(acc, v4, d4); dq8(acc, v5, d5); dq8(acc, v6, d6); dq8(acc, v7, d7);
    K += ((d0 + d1) + (d2 + d3)) + ((d4 + d5) + (d6 + d7));
  }
  if (j < e) {
    us8 ev = *(const us8*)(csr + j);
#pragma unroll
    for (int t = 0; t < 8; ++t) {
      if (j + t < e) {
        const int it = ev[t];
        const float dt = sc2[it];
        dq8(acc, hs[(long)it * L + lf], dt);
        K += dt;
      }
    }
  }
  const float d = dis[n];
  const float kc = 128.f * K;
  const int f8 = lf * 8;
  const float4 b0 = *(const float4*)(bias + f8);
  const float4 b1v = *(const float4*)(bias + f8 + 4);
  float4 o0, o1;
  o0.x = (acc[0] - kc) * d + b0.x;
  o0.y = (acc[1] - kc) * d + b0.y;
  o0.z = (acc[2] - kc) * d + b0.z;
  o0.w = (acc[3] - kc) * d + b0.w;
  o1.x = (acc[4] - kc) * d + b1v.x;
  o1.y = (acc[5] - kc) * d + b1v.y;
  o1.z = (acc[6] - kc) * d + b1v.z;
  o1.w = (acc[7] - kc) * d + b1v.w;
  *(float4*)(out + (long)n * 64 + f8) = o0;
  *(float4*)(out + (long)n * 64 + f8 + 4) = o1;
}

extern "C" void kernel_launch(void* const* d_in, const int* in_sizes, int n_in,
                              void* d_out, int out_size, void* d_ws, size_t ws_size,
                              hipStream_t stream) {
  const float* x  = (const float*)d_in[0];
  const int*   ei = (const int*)d_in[1];   // [2,E] int32
  const float* W1 = (const float*)d_in[4];
  const float* b1 = (const float*)d_in[5];
  const float* W2 = (const float*)d_in[6];
  const float* b2 = (const float*)d_in[7];
  float* out = (float*)d_out;

  const int N = in_sizes[0] / 128;
  const int E = in_sizes[1] / 2;
  const int NBKT = cdiv_l(N, NPB);   // 98 (<=128; N<=65536 for 16-bit pack)
  const int NBE  = cdiv_l(E, EPB);   // 196
  const int G1   = cdiv_l(N, 64);    // 782 gemm1 blocks
  const int CAPB = NBE * SUBCAP;     // per-bucket ebuf window (15680)

  // workspace layout (4-byte elems):
  //   histg[NBE*MAXB] | off[Np] | deg[Np] | dis[Np] | scale[Np] | sd[Np]
  //   | s2[Np] | w2f[4096] | ebuf[NBKT*CAPB u32] | csr[NBKT*CAPW ushort]
  //   | h8[N*32 u32] | h2[N*16 u32]
  const long Np = (N + 64) & ~63L;
  int*    histg = (int*)d_ws;
  int*    off   = histg + (long)NBE * MAXB;
  int*    deg   = off + Np;
  float*  dis   = (float*)(deg + Np);
  float*  scale = dis + Np;
  float*  sd    = scale + Np;
  float*  s2    = sd + Np;
  u32*    w2f   = (u32*)(s2 + Np);       // 1024 slots * 4 u32 = 16 KB
  u32*    ebuf  = w2f + 4096;
  ushort* csr   = (ushort*)(ebuf + (long)NBKT * CAPB);
  u32*    h8    = (u32*)(csr + (long)NBKT * CAPW);
  u32*    h2    = h8 + (long)N * 32;

  // ---- fused front: partition || GEMM1+int8 || pack-W2 ----
  k_front<<<NBE + G1 + 4, 256, 0, stream>>>(ei, ebuf, histg, E, NBE, G1, x,
                                            W1, W2, w2f, h8, scale, N);

  // ---- per-bucket CSR finalize (+ sd fold, 8-aligned starts) ----
  k_csr<<<NBKT, NPB, 0, stream>>>(ebuf, histg, scale, off, deg, dis, sd, csr,
                                  NBE, N);

  // ---- gather1 (int8) + relu + GEMM2 fused + h2 int8 quantize ----
  k_gg<<<cdiv_l(N, 16), 256, 0, stream>>>((const uint2*)h8, off, deg, csr,
                                          dis, sd, b1, w2f, h2, s2, N);

  // ---- layer-2 gather (int8) + bias ----
  k_gather2<<<cdiv_l(N, 32), 256, 0, stream>>>((const uint2*)h2, off, deg, csr,
                                               dis, s2, b2, out, N);
}

// Round 7
// 161.821 us; speedup vs baseline: 1.0338x; 1.0338x over previous
//
#include <hip/hip_runtime.h>

// GCN link-prediction forward: 2× GCNConv (128->128 relu, 128->64) on
// N=50000 nodes, E=800000 random edges. fp32 compute, int8 messages.
//
// Algebra: with dis[n] = rsqrt(indeg[n]+1),
//   conv(x)[c] = ( sum_{r->c} h[r]*dis[r] + h[c]*dis[c] ) * dis[c] + b,
//   h = x@W (unscaled). Messages stored int8 (per-row scale, biased +128;
//   exact -128 correction via K = sum of scales).
//
// R2..R9: 2737 -> 169 us (CSR gather, MFMA, fusion, bucketed sort).
// R10: src-sorted gather: +1% -- locality falsified.
// R11: layer-1 messages int8 (169 -> 161 us).
// R12/R14: layer-2 int8; gather2 LATENCY-bound, not traffic-bound.
// R15: W1/W2 pre-packed bf16 fragment-major: 158.8.
// R16: gathers de-shuffled (direct 16B ushort8 idx loads, 8-padded CSR
//      starts): 152.1 us. BEST.
// R17: cooperative fusion: 301 us (grid.sync ~100us+/sync on 8 XCDs).
//      Also: k_gg+k_gather2+boundaries only ~6 us total.
// R18: dummy-pad + x2 unroll gathers: +4 (wasted pad loads). REVERTED.
// R19: sub-window partition + self-converted W1: +15.2 (k_csr slot
//      overhead doubled + W1 conversion). REVERTED. Lesson: never trade
//      per-edge work for dispatch count.
// R20: R16 exactly, minus the k_pack dispatch: cur -> hipMemsetAsync
//      (128B blit); w2f packed by 4 tail blocks of fused dispatch; GEMM1
//      blocks cooperatively convert W1 -> LDS bf16 fragments (coalesced
//      float4 reads, 64 bf16r/thread, ds_read_b128 B-frags, LDS reused
//      by epilogue after barrier). Zero added per-edge work.

typedef unsigned int u32;
typedef unsigned short ushort;
typedef __attribute__((ext_vector_type(8))) short short8;
typedef __attribute__((ext_vector_type(8))) unsigned short us8;
typedef __attribute__((ext_vector_type(4))) float floatx4;

static inline int cdiv_l(long a, int b) { return (int)((a + b - 1) / b); }

constexpr int NPB  = 512;    // nodes per bucket (2^9)
constexpr int EPB  = 4096;   // edges per partition block
constexpr int MAXB = 128;    // max buckets (N <= 65536)
constexpr int CAP  = 12288;  // per-bucket edge capacity
// raw mean 8163, +5sigma 8616; +8-pad overhead keeps worst case < CAP.

__device__ __forceinline__ u32 pack_bf16(float a, float b) {
  union { float f; u32 i; } ua, ub;
  ua.f = a; ub.f = b;
  u32 x = (ua.i + 0x7fffu + ((ua.i >> 16) & 1u)) >> 16;           // rne, low
  u32 y = (ub.i + 0x7fffu + ((ub.i >> 16) & 1u)) & 0xffff0000u;   // rne, high
  return x | y;
}

__device__ __forceinline__ short bf16r(float f) {
  union { float f; u32 i; } u; u.f = f;
  return (short)((u.i + 0x7fffu + ((u.i >> 16) & 1u)) >> 16);     // rne
}

// int8 dequant-accumulate: 8 biased uint8 -> acc += (float)q * sd
// (the -128 bias is corrected once per node via K = sum of sd).
__device__ __forceinline__ void dq8(float* a, uint2 v, float sd) {
  a[0] += (float)(v.x & 255u) * sd;
  a[1] += (float)((v.x >> 8) & 255u) * sd;
  a[2] += (float)((v.x >> 16) & 255u) * sd;
  a[3] += (float)(v.x >> 24) * sd;
  a[4] += (float)(v.y & 255u) * sd;
  a[5] += (float)((v.y >> 8) & 255u) * sd;
  a[6] += (float)((v.y >> 16) & 255u) * sd;
  a[7] += (float)(v.y >> 24) * sd;
}

// ---- dispatch 1 (fused): blocks [0,NBE): edge partition; [NBE,NBE+G1):
// ---- GEMM1 (W1 -> LDS frags) + int8; [NBE+G1,+4): pack W2 fragments.
__global__ __launch_bounds__(256) void k_fused1(
    const int* __restrict__ ei, int* __restrict__ cur, u32* __restrict__ ebuf,
    int E, int NBE, int G1,
    const float* __restrict__ x, const float* __restrict__ W1,
    const float* __restrict__ W2, u32* __restrict__ w2f,
    u32* __restrict__ h8, float* __restrict__ scale, int N) {
  __shared__ float eb[4][16 * 133];   // 34 KB union workspace
  const int tid = threadIdx.x;
  const int blk = blockIdx.x;

  if (blk >= NBE + G1) {
    // ===== pack W2: 128x64 -> 1024 slots (4 blocks x 256) =====
    const int s = (blk - NBE - G1) * 256 + tid;
    const int lane = s & 63, frag = s >> 6;
    const int kc = frag >> 2, cb = frag & 3;
    const float* src =
        W2 + (long)(kc * 32 + (lane >> 4) * 8) * 64 + cb * 16 + (lane & 15);
    u32 o[4];
#pragma unroll
    for (int p = 0; p < 4; ++p)
      o[p] = pack_bf16(src[(2 * p) * 64], src[(2 * p + 1) * 64]);
    *(uint4*)(w2f + (long)s * 4) = make_uint4(o[0], o[1], o[2], o[3]);
    return;
  }

  if (blk < NBE) {
    // ===== edge partition (counting sort pass 1), LDS edge cache =====
    u32* ecache = (u32*)&eb[0][0];          // 4096 u32 = 16 KB (in eb[0..1])
    int* hist   = (int*)&eb[2][0];          // MAXB ints (in eb[2])
    int* curs   = hist + MAXB;
    const int* ecol = ei + E;
    if (tid < MAXB) hist[tid] = 0;
    __syncthreads();
    const int base = blk * EPB;
#pragma unroll
    for (int j = 0; j < EPB / 256; ++j) {
      int e = base + j * 256 + tid;
      u32 pk = 0xffffffffu;
      if (e < E) {
        u32 r = (u32)ei[e];
        u32 c = (u32)ecol[e];
        pk = r | (c << 16);
        atomicAdd(hist + (c >> 9), 1);
      }
      ecache[j * 256 + tid] = pk;
    }
    __syncthreads();
    if (tid < MAXB) {
      int n = hist[tid];
      curs[tid] = tid * CAP + (n ? atomicAdd(cur + tid, n) : 0);
    }
    __syncthreads();
#pragma unroll
    for (int j = 0; j < EPB / 256; ++j) {
      u32 pk = ecache[j * 256 + tid];
      if (pk != 0xffffffffu) {
        u32 c = pk >> 16;
        int b = c >> 9;
        int p = atomicAdd(curs + b, 1);
        if (p < (b + 1) * CAP)  // overflow guard (statistically impossible)
          ebuf[p] = (pk & 0xffffu) | ((c & (NPB - 1)) << 16);
      }
    }
    return;
  }

  // ===== MFMA GEMM1: h8[row,:] = int8(x[row,:] @ W1), K=M=128 =====
  // Cooperative W1 -> LDS bf16 fragment pack (coalesced float4 reads).
  // Fragment layout: slot s = (kc*8+cb)*64 + lane; lane's short8 elem j =
  // bf16(W1[(kc*32 + (lane>>4)*8 + j)*128 + cb*16 + (lane&15)]).
  constexpr int NC = 8, LROW = 133;
  ushort* wl = (ushort*)&eb[0][0];   // 2048 slots * 8 ushort = 32 KB
  for (int i = tid; i < 4096; i += 256) {
    float4 v = ((const float4*)W1)[i];
    const int base = i << 2;                 // linear f32 idx = k*128 + m
    const int k = base >> 7, m = base & 127;
    const int slot =
        ((k >> 5) * 8 + (m >> 4)) * 64 + ((k >> 3) & 3) * 16 + (m & 15);
    const int s8 = slot * 8 + (k & 7);
    wl[s8]      = (ushort)bf16r(v.x);
    wl[s8 + 8]  = (ushort)bf16r(v.y);       // m+1 -> slot+1 (l4+1 <= 15)
    wl[s8 + 16] = (ushort)bf16r(v.z);
    wl[s8 + 24] = (ushort)bf16r(v.w);
  }
  __syncthreads();

  const int w = tid >> 6, lane = tid & 63;
  const int quad = lane >> 4, n16 = lane & 15;
  const int row0 = ((blk - NBE) * 4 + w) * 16;

  floatx4 acc[NC];
#pragma unroll
  for (int c = 0; c < NC; ++c) acc[c] = {0.f, 0.f, 0.f, 0.f};

  const int am = row0 + n16;
  const bool av = am < N;
  const float* arow = x + (long)am * 128;
  const short8* wf = (const short8*)wl;

#pragma unroll
  for (int kc = 0; kc < 4; ++kc) {
    const int kb = kc * 32 + quad * 8;
    float4 a0 = make_float4(0.f, 0.f, 0.f, 0.f);
    float4 a1 = make_float4(0.f, 0.f, 0.f, 0.f);
    if (av) {
      a0 = *(const float4*)(arow + kb);
      a1 = *(const float4*)(arow + kb + 4);
    }
    short8 af;
    af[0] = bf16r(a0.x); af[1] = bf16r(a0.y); af[2] = bf16r(a0.z); af[3] = bf16r(a0.w);
    af[4] = bf16r(a1.x); af[5] = bf16r(a1.y); af[6] = bf16r(a1.z); af[7] = bf16r(a1.w);
#pragma unroll
    for (int c = 0; c < NC; ++c) {
      short8 bf = wf[(kc * 8 + c) * 64 + lane];   // ds_read_b128
      acc[c] = __builtin_amdgcn_mfma_f32_16x16x32_bf16(af, bf, acc[c], 0, 0, 0);
    }
  }
  __syncthreads();   // all wl reads done before epilogue reuses eb

  float* ep = eb[w];
#pragma unroll
  for (int c = 0; c < NC; ++c)
#pragma unroll
    for (int r = 0; r < 4; ++r)
      ep[(quad * 4 + r) * LROW + c * 16 + n16] = acc[c][r];
  __syncthreads();

  // int8 quantize: lane -> row rr = lane>>2, col segment seg*32..+31
  const int rr = lane >> 2, seg = lane & 3;
  const float* rowp = ep + rr * LROW + seg * 32;
  float m = 0.f;
#pragma unroll
  for (int c = 0; c < 32; ++c) m = fmaxf(m, fabsf(rowp[c]));
  m = fmaxf(m, __shfl_xor(m, 1, 4));
  m = fmaxf(m, __shfl_xor(m, 2, 4));
  const float inv = (m > 0.f) ? 127.f / m : 0.f;
  const float s = m / 127.f;
  u32 q[8];
#pragma unroll
  for (int wd = 0; wd < 8; ++wd) {
    u32 b0 = (u32)((int)rintf(rowp[wd * 4 + 0] * inv) + 128);
    u32 b1 = (u32)((int)rintf(rowp[wd * 4 + 1] * inv) + 128);
    u32 b2 = (u32)((int)rintf(rowp[wd * 4 + 2] * inv) + 128);
    u32 b3 = (u32)((int)rintf(rowp[wd * 4 + 3] * inv) + 128);
    q[wd] = (b0 & 255u) | ((b1 & 255u) << 8) | ((b2 & 255u) << 16) | (b3 << 24);
  }
  const int rg = row0 + rr;
  if (rg < N) {
    uint4* dst = (uint4*)(h8 + (long)rg * 32 + seg * 8);
    dst[0] = make_uint4(q[0], q[1], q[2], q[3]);
    dst[1] = make_uint4(q[4], q[5], q[6], q[7]);
    if (seg == 0) scale[rg] = s;
  }
}

// ---- dispatch 2: per-bucket CSR finalize + sd fold; node list starts ----
// ---- padded to 8 entries so gathers can use aligned 16B index loads. ----
__global__ __launch_bounds__(NPB) void k_csr(const u32* __restrict__ ebuf,
                                             const int* __restrict__ cur,
                                             const float* __restrict__ scale,
                                             int* __restrict__ off,
                                             int* __restrict__ deg,
                                             float* __restrict__ dis,
                                             float* __restrict__ sd,
                                             ushort* __restrict__ csr, int N) {
  __shared__ int cnt[NPB];
  __shared__ int curl[NPB];
  __shared__ int wsum[NPB / 64];
  const int tid = threadIdx.x;
  const int b = blockIdx.x;
  const int s = b * CAP;
  const int e = s + min(cur[b], CAP);
  cnt[tid] = 0;
  __syncthreads();
  for (int i = s + tid; i < e; i += NPB)
    atomicAdd(cnt + (ebuf[i] >> 16), 1);
  __syncthreads();
  const int lane = tid & 63, w = tid >> 6;
  const int v = cnt[tid];
  const int vp = (v + 7) & ~7;    // padded length (8-aligned starts)
  int incl = vp;
#pragma unroll
  for (int d = 1; d < 64; d <<= 1) {
    int x = __shfl_up(incl, d, 64);
    if (lane >= d) incl += x;
  }
  if (lane == 63) wsum[w] = incl;
  __syncthreads();
  if (w == 0 && lane < NPB / 64) {
    int sv = wsum[lane];
#pragma unroll
    for (int d = 1; d < NPB / 64; d <<= 1) {
      int x = __shfl_up(sv, d, 64);
      if (lane >= d) sv += x;
    }
    wsum[lane] = sv;
  }
  __syncthreads();
  int excl = ((w > 0) ? wsum[w - 1] : 0) + incl - vp;
  int node = b * NPB + tid;
  if (node < N) {
    float dv = rsqrtf((float)v + 1.0f);
    off[node] = s + excl;
    deg[node] = v;
    dis[node] = dv;
    sd[node] = scale[node] * dv;
  }
  curl[tid] = excl;
  __syncthreads();
  for (int i = s + tid; i < e; i += NPB) {
    u32 pk = ebuf[i];
    int p = atomicAdd(curl + (pk >> 16), 1);
    csr[s + p] = (ushort)(pk & 0xffffu);
  }
}

// ---- dispatch 3: fused gather1 (int8 msgs, direct idx loads) + relu +
// ---- GEMM2; epilogue quantizes h2 to int8 (per-row scale s2). ----
__global__ __launch_bounds__(256) void k_gg(
    const uint2* __restrict__ h8, const int* __restrict__ off,
    const int* __restrict__ deg, const ushort* __restrict__ csr,
    const float* __restrict__ dis, const float* __restrict__ sd,
    const float* __restrict__ b1, const u32* __restrict__ w2f,
    u32* __restrict__ h2, float* __restrict__ s2, int N) {
  constexpr int LG = 65;   // u32 words per g row (64 + pad)
  constexpr int LC = 66;   // f32 words per C row (64 + pad)
  __shared__ u32 lg[16 * LG];
  __shared__ float cb[16 * LC];
  const int tid = threadIdx.x;
  const int r = tid >> 4;          // local node 0..15
  const int lf = tid & 15;         // lane within 16-group (8-byte chunk)
  const int row0 = blockIdx.x * 16;
  const int n = row0 + r;

  // ---- phase 1: int8 gather (rows = 128B = 2 lines) ----
  u32 gw[4] = {0, 0, 0, 0};
  if (n < N) {
    const int s = off[n], e = s + deg[n];
    const float dn = dis[n];
    float acc[8] = {};
    float K = 0.f;
    {
      float sn = sd[n];
      dq8(acc, h8[(long)n * 16 + lf], sn);  // self-loop
      K += sn;
    }
    int j = s;
    for (; j + 8 <= e; j += 8) {
      us8 ev = *(const us8*)(csr + j);   // 16B aligned broadcast load
      const int i0 = ev[0], i1 = ev[1], i2 = ev[2], i3 = ev[3];
      const int i4 = ev[4], i5 = ev[5], i6 = ev[6], i7 = ev[7];
      const float d0 = sd[i0], d1 = sd[i1], d2 = sd[i2], d3 = sd[i3];
      const float d4 = sd[i4], d5 = sd[i5], d6 = sd[i6], d7 = sd[i7];
      uint2 v0 = h8[(long)i0 * 16 + lf];
      uint2 v1 = h8[(long)i1 * 16 + lf];
      uint2 v2 = h8[(long)i2 * 16 + lf];
      uint2 v3 = h8[(long)i3 * 16 + lf];
      uint2 v4 = h8[(long)i4 * 16 + lf];
      uint2 v5 = h8[(long)i5 * 16 + lf];
      uint2 v6 = h8[(long)i6 * 16 + lf];
      uint2 v7 = h8[(long)i7 * 16 + lf];
      dq8(acc, v0, d0); dq8(acc, v1, d1); dq8(acc, v2, d2); dq8(acc, v3, d3);
      dq8(acc, v4, d4); dq8(acc, v5, d5); dq8(acc, v6, d6); dq8(acc, v7, d7);
      K += ((d0 + d1) + (d2 + d3)) + ((d4 + d5) + (d6 + d7));
    }
    if (j < e) {
      us8 ev = *(const us8*)(csr + j);
#pragma unroll
      for (int t = 0; t < 8; ++t) {
        if (j + t < e) {
          const int it = ev[t];
          const float dt = sd[it];
          dq8(acc, h8[(long)it * 16 + lf], dt);
          K += dt;
        }
      }
    }
    const int f8 = lf * 8;
    const float4 bv0 = *(const float4*)(b1 + f8);
    const float4 bv1 = *(const float4*)(b1 + f8 + 4);
    const float bb[8] = {bv0.x, bv0.y, bv0.z, bv0.w, bv1.x, bv1.y, bv1.z, bv1.w};
    const float kc = 128.f * K;
#pragma unroll
    for (int q = 0; q < 8; ++q)
      acc[q] = fmaxf((acc[q] - kc) * dn + bb[q], 0.f);
#pragma unroll
    for (int q = 0; q < 4; ++q)
      gw[q] = pack_bf16(acc[2 * q], acc[2 * q + 1]);
  }
#pragma unroll
  for (int q = 0; q < 4; ++q) lg[r * LG + lf * 4 + q] = gw[q];
  __syncthreads();

  // ---- phase 2: 16x128x64 MFMA; wave w owns cols w*16..w*16+15 ----
  const int w = tid >> 6, lane = tid & 63;
  const int quad = lane >> 4, n16 = lane & 15;
  floatx4 acc4 = {0.f, 0.f, 0.f, 0.f};
#pragma unroll
  for (int kc = 0; kc < 4; ++kc) {
    const int kb = kc * 32 + quad * 8;
    const u32* ap = &lg[n16 * LG + (kb >> 1)];
    u32 aw[4] = {ap[0], ap[1], ap[2], ap[3]};
    short8 af = *(short8*)aw;
    short8 bf = ((const short8*)w2f)[(kc * 4 + w) * 64 + lane];
    acc4 = __builtin_amdgcn_mfma_f32_16x16x32_bf16(af, bf, acc4, 0, 0, 0);
  }
  float dd[4];
#pragma unroll
  for (int r4 = 0; r4 < 4; ++r4) {
    int rg = row0 + quad * 4 + r4;
    dd[r4] = (rg < N) ? dis[rg] : 0.f;
  }
#pragma unroll
  for (int r4 = 0; r4 < 4; ++r4)
    cb[(quad * 4 + r4) * LC + w * 16 + n16] = acc4[r4] * dd[r4];
  __syncthreads();

  // ---- int8 quantize h2 rows: 16 lanes per row, 4 cols each ----
  const int rr2 = tid >> 4, lf2 = tid & 15;
  const float* rp = cb + rr2 * LC + lf2 * 4;
  float mx = fmaxf(fmaxf(fabsf(rp[0]), fabsf(rp[1])),
                   fmaxf(fabsf(rp[2]), fabsf(rp[3])));
  mx = fmaxf(mx, __shfl_xor(mx, 1, 16));
  mx = fmaxf(mx, __shfl_xor(mx, 2, 16));
  mx = fmaxf(mx, __shfl_xor(mx, 4, 16));
  mx = fmaxf(mx, __shfl_xor(mx, 8, 16));
  const float inv2 = (mx > 0.f) ? 127.f / mx : 0.f;
  const int rg2 = row0 + rr2;
  if (rg2 < N) {
    u32 q0 = (u32)((int)rintf(rp[0] * inv2) + 128);
    u32 q1 = (u32)((int)rintf(rp[1] * inv2) + 128);
    u32 q2 = (u32)((int)rintf(rp[2] * inv2) + 128);
    u32 q3 = (u32)((int)rintf(rp[3] * inv2) + 128);
    h2[(long)rg2 * 16 + lf2] =
        (q0 & 255u) | ((q1 & 255u) << 8) | ((q2 & 255u) << 16) | (q3 << 24);
    if (lf2 == 0) s2[rg2] = mx / 127.f;
  }
}

// ---- dispatch 4: layer-2 gather (int8 h2, direct idx loads) + bias ----
__global__ __launch_bounds__(256) void k_gather2(
    const uint2* __restrict__ hs, const int* __restrict__ off,
    const int* __restrict__ deg, const ushort* __restrict__ csr,
    const float* __restrict__ dis, const float* __restrict__ sc2,
    const float* __restrict__ bias, float* __restrict__ out, int N) {
  constexpr int L = 8;  // lanes per node
  const int local = threadIdx.x / L;
  const int lf = threadIdx.x % L;
  const int n = blockIdx.x * (256 / L) + local;
  if (n >= N) return;
  const int s = off[n], e = s + deg[n];
  float acc[8] = {};
  float K = 0.f;
  {
    float t0 = sc2[n];
    dq8(acc, hs[(long)n * L + lf], t0);  // self-loop
    K += t0;
  }
  int j = s;
  for (; j + 8 <= e; j += 8) {
    us8 ev = *(const us8*)(csr + j);   // 16B aligned broadcast load
    const int i0 = ev[0], i1 = ev[1], i2 = ev[2], i3 = ev[3];
    const int i4 = ev[4], i5 = ev[5], i6 = ev[6], i7 = ev[7];
    const float d0 = sc2[i0], d1 = sc2[i1], d2 = sc2[i2], d3 = sc2[i3];
    const float d4 = sc2[i4], d5 = sc2[i5], d6 = sc2[i6], d7 = sc2[i7];
    uint2 v0 = hs[(long)i0 * L + lf];
    uint2 v1 = hs[(long)i1 * L + lf];
    uint2 v2 = hs[(long)i2 * L + lf];
    uint2 v3 = hs[(long)i3 * L + lf];
    uint2 v4 = hs[(long)i4 * L + lf];
    uint2 v5 = hs[(long)i5 * L + lf];
    uint2 v6 = hs[(long)i6 * L + lf];
    uint2 v7 = hs[(long)i7 * L + lf];
    dq8(acc, v0, d0); dq8(acc, v1, d1); dq8(acc, v2, d2); dq8(acc, v3, d3);
    dq8(acc, v4, d4); dq8(acc, v5, d5); dq8(acc, v6, d6); dq8(acc, v7, d7);
    K += ((d0 + d1) + (d2 + d3)) + ((d4 + d5) + (d6 + d7));
  }
  if (j < e) {
    us8 ev = *(const us8*)(csr + j);
#pragma unroll
    for (int t = 0; t < 8; ++t) {
      if (j + t < e) {
        const int it = ev[t];
        const float dt = sc2[it];
        dq8(acc, hs[(long)it * L + lf], dt);
        K += dt;
      }
    }
  }
  const float d = dis[n];
  const float kc = 128.f * K;
  const int f8 = lf * 8;
  const float4 b0 = *(const float4*)(bias + f8);
  const float4 b1v = *(const float4*)(bias + f8 + 4);
  float4 o0, o1;
  o0.x = (acc[0] - kc) * d + b0.x;
  o0.y = (acc[1] - kc) * d + b0.y;
  o0.z = (acc[2] - kc) * d + b0.z;
  o0.w = (acc[3] - kc) * d + b0.w;
  o1.x = (acc[4] - kc) * d + b1v.x;
  o1.y = (acc[5] - kc) * d + b1v.y;
  o1.z = (acc[6] - kc) * d + b1v.z;
  o1.w = (acc[7] - kc) * d + b1v.w;
  *(float4*)(out + (long)n * 64 + f8) = o0;
  *(float4*)(out + (long)n * 64 + f8 + 4) = o1;
}

extern "C" void kernel_launch(void* const* d_in, const int* in_sizes, int n_in,
                              void* d_out, int out_size, void* d_ws, size_t ws_size,
                              hipStream_t stream) {
  const float* x  = (const float*)d_in[0];
  const int*   ei = (const int*)d_in[1];   // [2,E] int32
  const float* W1 = (const float*)d_in[4];
  const float* b1 = (const float*)d_in[5];
  const float* W2 = (const float*)d_in[6];
  const float* b2 = (const float*)d_in[7];
  float* out = (float*)d_out;

  const int N = in_sizes[0] / 128;
  const int E = in_sizes[1] / 2;
  const int NBKT = cdiv_l(N, NPB);   // 98 (<=128; N<=65536 for 16-bit pack)
  const int NBE  = cdiv_l(E, EPB);   // 196
  const int G1   = cdiv_l(N, 64);    // 782 gemm1 blocks

  // workspace layout (4-byte elems):
  //   cur[128] | off[Np] | deg[Np] | dis[Np] | scale[Np] | sd[Np] | s2[Np]
  //   | w2f[4096] | ebuf[BW u32] | csr[BW ushort] | h8[N*32 u32]
  //   | h2[N*16 u32]
  const long Np = (N + 64) & ~63L;
  const long BW = (long)NBKT * CAP;
  int*    cur   = (int*)d_ws;
  int*    off   = cur + 128;
  int*    deg   = off + Np;
  float*  dis   = (float*)(deg + Np);
  float*  scale = dis + Np;
  float*  sd    = scale + Np;
  float*  s2    = sd + Np;
  u32*    w2f   = (u32*)(s2 + Np);       // 1024 slots * 4 u32 = 16 KB
  u32*    ebuf  = w2f + 4096;
  ushort* csr   = (ushort*)(ebuf + BW);
  u32*    h8    = (u32*)(csr + BW);      // BW ushorts = BW/2 u32 words
  u32*    h2    = h8 + (long)N * 32;

  // ---- cursors -> 0 (tiny DMA blit) ----
  hipMemsetAsync(cur, 0, MAXB * sizeof(int), stream);

  // ---- fused: partition || GEMM1+int8 (W1->LDS frags) || pack-W2 ----
  k_fused1<<<NBE + G1 + 4, 256, 0, stream>>>(ei, cur, ebuf, E, NBE, G1, x,
                                             W1, W2, w2f, h8, scale, N);

  // ---- per-bucket CSR finalize (+ sd fold, 8-aligned starts) ----
  k_csr<<<NBKT, NPB, 0, stream>>>(ebuf, cur, scale, off, deg, dis, sd, csr, N);

  // ---- gather1 (int8) + relu + GEMM2 fused + h2 int8 quantize ----
  k_gg<<<cdiv_l(N, 16), 256, 0, stream>>>((const uint2*)h8, off, deg, csr,
                                          dis, sd, b1, w2f, h2, s2, N);

  // ---- layer-2 gather (int8) + bias ----
  k_gather2<<<cdiv_l(N, 32), 256, 0, stream>>>((const uint2*)h2, off, deg, csr,
                                               dis, s2, b2, out, N);
}

// Round 8
// 149.432 us; speedup vs baseline: 1.1195x; 1.0829x over previous
//
#include <hip/hip_runtime.h>

// GCN link-prediction forward: 2× GCNConv (128->128 relu, 128->64) on
// N=50000 nodes, E=800000 random edges. fp32 compute, int8 messages.
//
// Algebra: with dis[n] = rsqrt(indeg[n]+1),
//   conv(x)[c] = ( sum_{r->c} h[r]*dis[r] + h[c]*dis[c] ) * dis[c] + b,
//   h = x@W (unscaled). Messages stored int8 (per-row scale, biased +128;
//   exact -128 correction via K = sum of scales).
//
// R2..R9: 2737 -> 169 us (CSR gather, MFMA, fusion, bucketed sort).
// R10: src-sorted gather: +1% -- locality falsified.
// R11: layer-1 messages int8 (169 -> 161 us).
// R12/R14: layer-2 int8; gather2 LATENCY-bound, not traffic-bound.
// R15: W1/W2 pre-packed bf16 fragment-major (k_pack): 158.8.
// R16: gathers de-shuffled (direct 16B ushort8 idx loads, 8-padded CSR
//      starts): 152.1 us. BEST.
// R17: cooperative fusion: 301 us (grid.sync ~100us+/sync). REVERTED.
//      Key datum: k_gg + k_gather2 + boundaries = ~6 us total.
// R18: dummy-pad + x2 unroll gathers: +4. REVERTED.
// R19: sub-window partition + self-converted W1: +15. REVERTED.
// R20: in-block W1->LDS conversion: +9.7 (782x redundant conversion).
//      REVERTED. Lesson x3: never trade dispatch count for per-block work.
// R21: exact R16 + k_csr latency fix (the one untouched kernel):
//      1024 threads (chain depth 16->8 per pass) + LDS edge cache
//      (pass 2 reads LDS, not global). Everything else byte-identical.

typedef unsigned int u32;
typedef unsigned short ushort;
typedef __attribute__((ext_vector_type(8))) short short8;
typedef __attribute__((ext_vector_type(8))) unsigned short us8;
typedef __attribute__((ext_vector_type(4))) float floatx4;

static inline int cdiv_l(long a, int b) { return (int)((a + b - 1) / b); }

constexpr int NPB  = 512;    // nodes per bucket (2^9)
constexpr int EPB  = 4096;   // edges per partition block
constexpr int MAXB = 128;    // max buckets (N <= 65536)
constexpr int CAP  = 12288;  // per-bucket edge capacity
// raw mean 8163, +5sigma 8616; +8-pad overhead keeps worst case < CAP.

__device__ __forceinline__ u32 pack_bf16(float a, float b) {
  union { float f; u32 i; } ua, ub;
  ua.f = a; ub.f = b;
  u32 x = (ua.i + 0x7fffu + ((ua.i >> 16) & 1u)) >> 16;           // rne, low
  u32 y = (ub.i + 0x7fffu + ((ub.i >> 16) & 1u)) & 0xffff0000u;   // rne, high
  return x | y;
}

__device__ __forceinline__ short bf16r(float f) {
  union { float f; u32 i; } u; u.f = f;
  return (short)((u.i + 0x7fffu + ((u.i >> 16) & 1u)) >> 16);     // rne
}

// int8 dequant-accumulate: 8 biased uint8 -> acc += (float)q * sd
// (the -128 bias is corrected once per node via K = sum of sd).
__device__ __forceinline__ void dq8(float* a, uint2 v, float sd) {
  a[0] += (float)(v.x & 255u) * sd;
  a[1] += (float)((v.x >> 8) & 255u) * sd;
  a[2] += (float)((v.x >> 16) & 255u) * sd;
  a[3] += (float)(v.x >> 24) * sd;
  a[4] += (float)(v.y & 255u) * sd;
  a[5] += (float)((v.y >> 8) & 255u) * sd;
  a[6] += (float)((v.y >> 16) & 255u) * sd;
  a[7] += (float)(v.y >> 24) * sd;
}

// ---- dispatch 0: zero cursors + pack W1/W2 into MFMA B-fragment bf16 ----
// Fragment layout: slot s = frag*64 + lane; frag = kc*(M/16) + cb.
// Lane's short8: elem j = bf16(W[(kc*32 + (lane>>4)*8 + j)*M + cb*16 + (lane&15)])
// so GEMM B-load is ONE coalesced 16B read, zero conversion VALU.
__global__ __launch_bounds__(256) void k_pack(
    const float* __restrict__ W1, const float* __restrict__ W2,
    u32* __restrict__ w1f, u32* __restrict__ w2f, int* __restrict__ cur) {
  const int tid = threadIdx.x;
  const int b = blockIdx.x;
  if (b == 0 && tid < MAXB) cur[tid] = 0;
  if (b < 8) {
    // W1: 128x128 -> 2048 slots (8 blocks x 256)
    const int s = b * 256 + tid;
    const int lane = s & 63, frag = s >> 6;
    const int kc = frag >> 3, cb = frag & 7;
    const float* src =
        W1 + (long)(kc * 32 + (lane >> 4) * 8) * 128 + cb * 16 + (lane & 15);
    u32 o[4];
#pragma unroll
    for (int p = 0; p < 4; ++p)
      o[p] = pack_bf16(src[(2 * p) * 128], src[(2 * p + 1) * 128]);
    *(uint4*)(w1f + (long)s * 4) = make_uint4(o[0], o[1], o[2], o[3]);
  } else {
    // W2: 128x64 -> 1024 slots (4 blocks x 256)
    const int s = (b - 8) * 256 + tid;
    const int lane = s & 63, frag = s >> 6;
    const int kc = frag >> 2, cb = frag & 3;
    const float* src =
        W2 + (long)(kc * 32 + (lane >> 4) * 8) * 64 + cb * 16 + (lane & 15);
    u32 o[4];
#pragma unroll
    for (int p = 0; p < 4; ++p)
      o[p] = pack_bf16(src[(2 * p) * 64], src[(2 * p + 1) * 64]);
    *(uint4*)(w2f + (long)s * 4) = make_uint4(o[0], o[1], o[2], o[3]);
  }
}

// ---- fused dispatch 1: blocks [0,NBE) partition edges into bucket windows;
// ---- blocks [NBE,..) compute h8 = int8(x@W1) + per-row scale (no dis).
__global__ __launch_bounds__(256) void k_fused1(
    const int* __restrict__ ei, int* __restrict__ cur, u32* __restrict__ ebuf,
    int E, int NBE,
    const float* __restrict__ x, const u32* __restrict__ w1f,
    u32* __restrict__ h8, float* __restrict__ scale, int N) {
  __shared__ float eb[4][16 * 133];   // gemm epilogue staging (34 KB)
  const int tid = threadIdx.x;

  if (blockIdx.x < (unsigned)NBE) {
    // ===== edge partition (counting sort pass 1), LDS edge cache =====
    u32* ecache = (u32*)&eb[0][0];          // 4096 u32 = 16 KB (in eb[0..1])
    int* hist   = (int*)&eb[2][0];          // MAXB ints (in eb[2])
    int* curs   = hist + MAXB;
    const int* ecol = ei + E;
    if (tid < MAXB) hist[tid] = 0;
    __syncthreads();
    const int base = blockIdx.x * EPB;
#pragma unroll
    for (int j = 0; j < EPB / 256; ++j) {
      int e = base + j * 256 + tid;
      u32 pk = 0xffffffffu;
      if (e < E) {
        u32 r = (u32)ei[e];
        u32 c = (u32)ecol[e];
        pk = r | (c << 16);
        atomicAdd(hist + (c >> 9), 1);
      }
      ecache[j * 256 + tid] = pk;
    }
    __syncthreads();
    if (tid < MAXB) {
      int n = hist[tid];
      curs[tid] = tid * CAP + (n ? atomicAdd(cur + tid, n) : 0);
    }
    __syncthreads();
#pragma unroll
    for (int j = 0; j < EPB / 256; ++j) {
      u32 pk = ecache[j * 256 + tid];
      if (pk != 0xffffffffu) {
        u32 c = pk >> 16;
        int b = c >> 9;
        int p = atomicAdd(curs + b, 1);
        if (p < (b + 1) * CAP)  // overflow guard (statistically impossible)
          ebuf[p] = (pk & 0xffffu) | ((c & (NPB - 1)) << 16);
      }
    }
    return;
  }

  // ===== MFMA GEMM1: h8[row,:] = int8(x[row,:] @ W1), K=M=128 =====
  constexpr int K = 128, NC = 8, LROW = 133;
  const int w = tid >> 6, lane = tid & 63;
  const int quad = lane >> 4, n16 = lane & 15;
  const int row0 = ((blockIdx.x - NBE) * 4 + w) * 16;

  floatx4 acc[NC];
#pragma unroll
  for (int c = 0; c < NC; ++c) acc[c] = {0.f, 0.f, 0.f, 0.f};

  const int am = row0 + n16;
  const bool av = am < N;
  const float* arow = x + (long)am * K;
  const short8* wf = (const short8*)w1f;

#pragma unroll
  for (int kc = 0; kc < 4; ++kc) {
    const int kb = kc * 32 + quad * 8;
    float4 a0 = make_float4(0.f, 0.f, 0.f, 0.f);
    float4 a1 = make_float4(0.f, 0.f, 0.f, 0.f);
    if (av) {
      a0 = *(const float4*)(arow + kb);
      a1 = *(const float4*)(arow + kb + 4);
    }
    short8 af;
    af[0] = bf16r(a0.x); af[1] = bf16r(a0.y); af[2] = bf16r(a0.z); af[3] = bf16r(a0.w);
    af[4] = bf16r(a1.x); af[5] = bf16r(a1.y); af[6] = bf16r(a1.z); af[7] = bf16r(a1.w);
#pragma unroll
    for (int c = 0; c < NC; ++c) {
      short8 bf = wf[(kc * 8 + c) * 64 + lane];
      acc[c] = __builtin_amdgcn_mfma_f32_16x16x32_bf16(af, bf, acc[c], 0, 0, 0);
    }
  }

  float* ep = eb[w];
#pragma unroll
  for (int c = 0; c < NC; ++c)
#pragma unroll
    for (int r = 0; r < 4; ++r)
      ep[(quad * 4 + r) * LROW + c * 16 + n16] = acc[c][r];
  __syncthreads();

  // int8 quantize: lane -> row rr = lane>>2, col segment seg*32..+31
  const int rr = lane >> 2, seg = lane & 3;
  const float* rowp = ep + rr * LROW + seg * 32;
  float m = 0.f;
#pragma unroll
  for (int c = 0; c < 32; ++c) m = fmaxf(m, fabsf(rowp[c]));
  m = fmaxf(m, __shfl_xor(m, 1, 4));
  m = fmaxf(m, __shfl_xor(m, 2, 4));
  const float inv = (m > 0.f) ? 127.f / m : 0.f;
  const float s = m / 127.f;
  u32 q[8];
#pragma unroll
  for (int wd = 0; wd < 8; ++wd) {
    u32 b0 = (u32)((int)rintf(rowp[wd * 4 + 0] * inv) + 128);
    u32 b1 = (u32)((int)rintf(rowp[wd * 4 + 1] * inv) + 128);
    u32 b2 = (u32)((int)rintf(rowp[wd * 4 + 2] * inv) + 128);
    u32 b3 = (u32)((int)rintf(rowp[wd * 4 + 3] * inv) + 128);
    q[wd] = (b0 & 255u) | ((b1 & 255u) << 8) | ((b2 & 255u) << 16) | (b3 << 24);
  }
  const int rg = row0 + rr;
  if (rg < N) {
    uint4* dst = (uint4*)(h8 + (long)rg * 32 + seg * 8);
    dst[0] = make_uint4(q[0], q[1], q[2], q[3]);
    dst[1] = make_uint4(q[4], q[5], q[6], q[7]);
    if (seg == 0) scale[rg] = s;
  }
}

// ---- dispatch 2: per-bucket CSR finalize + sd fold; starts padded to 8.
// ---- R21: 1024 threads (chain depth halved) + LDS edge cache (pass 2
// ---- reads LDS, not global). Scan on first 512 threads (wave-aligned).
__global__ __launch_bounds__(1024) void k_csr(const u32* __restrict__ ebuf,
                                              const int* __restrict__ cur,
                                              const float* __restrict__ scale,
                                              int* __restrict__ off,
                                              int* __restrict__ deg,
                                              float* __restrict__ dis,
                                              float* __restrict__ sd,
                                              ushort* __restrict__ csr, int N) {
  __shared__ u32 ecache[CAP];     // 48 KB edge cache
  __shared__ int cnt[NPB];
  __shared__ int curl[NPB];
  __shared__ int wsum[NPB / 64];
  const int tid = threadIdx.x;
  const int b = blockIdx.x;
  const int s = b * CAP;
  const int e = s + min(cur[b], CAP);
  if (tid < NPB) cnt[tid] = 0;
  __syncthreads();
  for (int i = s + tid; i < e; i += 1024) {
    u32 pk = ebuf[i];
    ecache[i - s] = pk;
    atomicAdd(cnt + (pk >> 16), 1);
  }
  __syncthreads();
  const int lane = tid & 63, w = tid >> 6;
  int v = 0, vp = 0, incl = 0;
  if (tid < NPB) {                 // waves 0..7 (uniform per wave)
    v = cnt[tid];
    vp = (v + 7) & ~7;             // padded length (8-aligned starts)
    incl = vp;
#pragma unroll
    for (int d = 1; d < 64; d <<= 1) {
      int x = __shfl_up(incl, d, 64);
      if (lane >= d) incl += x;
    }
    if (lane == 63) wsum[w] = incl;
  }
  __syncthreads();
  if (w == 0 && lane < NPB / 64) {
    int sv = wsum[lane];
#pragma unroll
    for (int d = 1; d < NPB / 64; d <<= 1) {
      int x = __shfl_up(sv, d, 64);
      if (lane >= d) sv += x;
    }
    wsum[lane] = sv;
  }
  __syncthreads();
  if (tid < NPB) {
    const int excl = ((w > 0) ? wsum[w - 1] : 0) + incl - vp;
    const int node = b * NPB + tid;
    if (node < N) {
      float dv = rsqrtf((float)v + 1.0f);
      off[node] = s + excl;
      deg[node] = v;
      dis[node] = dv;
      sd[node] = scale[node] * dv;
    }
    curl[tid] = excl;
  }
  __syncthreads();
  for (int i = s + tid; i < e; i += 1024) {
    u32 pk = ecache[i - s];
    int p = atomicAdd(curl + (pk >> 16), 1);
    csr[s + p] = (ushort)(pk & 0xffffu);
  }
}

// ---- dispatch 3: fused gather1 (int8 msgs, direct idx loads) + relu +
// ---- GEMM2; epilogue quantizes h2 to int8 (per-row scale s2). ----
__global__ __launch_bounds__(256) void k_gg(
    const uint2* __restrict__ h8, const int* __restrict__ off,
    const int* __restrict__ deg, const ushort* __restrict__ csr,
    const float* __restrict__ dis, const float* __restrict__ sd,
    const float* __restrict__ b1, const u32* __restrict__ w2f,
    u32* __restrict__ h2, float* __restrict__ s2, int N) {
  constexpr int LG = 65;   // u32 words per g row (64 + pad)
  constexpr int LC = 66;   // f32 words per C row (64 + pad)
  __shared__ u32 lg[16 * LG];
  __shared__ float cb[16 * LC];
  const int tid = threadIdx.x;
  const int r = tid >> 4;          // local node 0..15
  const int lf = tid & 15;         // lane within 16-group (8-byte chunk)
  const int row0 = blockIdx.x * 16;
  const int n = row0 + r;

  // ---- phase 1: int8 gather (rows = 128B = 2 lines) ----
  u32 gw[4] = {0, 0, 0, 0};
  if (n < N) {
    const int s = off[n], e = s + deg[n];
    const float dn = dis[n];
    float acc[8] = {};
    float K = 0.f;
    {
      float sn = sd[n];
      dq8(acc, h8[(long)n * 16 + lf], sn);  // self-loop
      K += sn;
    }
    int j = s;
    for (; j + 8 <= e; j += 8) {
      us8 ev = *(const us8*)(csr + j);   // 16B aligned broadcast load
      const int i0 = ev[0], i1 = ev[1], i2 = ev[2], i3 = ev[3];
      const int i4 = ev[4], i5 = ev[5], i6 = ev[6], i7 = ev[7];
      const float d0 = sd[i0], d1 = sd[i1], d2 = sd[i2], d3 = sd[i3];
      const float d4 = sd[i4], d5 = sd[i5], d6 = sd[i6], d7 = sd[i7];
      uint2 v0 = h8[(long)i0 * 16 + lf];
      uint2 v1 = h8[(long)i1 * 16 + lf];
      uint2 v2 = h8[(long)i2 * 16 + lf];
      uint2 v3 = h8[(long)i3 * 16 + lf];
      uint2 v4 = h8[(long)i4 * 16 + lf];
      uint2 v5 = h8[(long)i5 * 16 + lf];
      uint2 v6 = h8[(long)i6 * 16 + lf];
      uint2 v7 = h8[(long)i7 * 16 + lf];
      dq8(acc, v0, d0); dq8(acc, v1, d1); dq8(acc, v2, d2); dq8(acc, v3, d3);
      dq8(acc, v4, d4); dq8(acc, v5, d5); dq8(acc, v6, d6); dq8(acc, v7, d7);
      K += ((d0 + d1) + (d2 + d3)) + ((d4 + d5) + (d6 + d7));
    }
    if (j < e) {
      us8 ev = *(const us8*)(csr + j);
#pragma unroll
      for (int t = 0; t < 8; ++t) {
        if (j + t < e) {
          const int it = ev[t];
          const float dt = sd[it];
          dq8(acc, h8[(long)it * 16 + lf], dt);
          K += dt;
        }
      }
    }
    const int f8 = lf * 8;
    const float4 bv0 = *(const float4*)(b1 + f8);
    const float4 bv1 = *(const float4*)(b1 + f8 + 4);
    const float bb[8] = {bv0.x, bv0.y, bv0.z, bv0.w, bv1.x, bv1.y, bv1.z, bv1.w};
    const float kc = 128.f * K;
#pragma unroll
    for (int q = 0; q < 8; ++q)
      acc[q] = fmaxf((acc[q] - kc) * dn + bb[q], 0.f);
#pragma unroll
    for (int q = 0; q < 4; ++q)
      gw[q] = pack_bf16(acc[2 * q], acc[2 * q + 1]);
  }
#pragma unroll
  for (int q = 0; q < 4; ++q) lg[r * LG + lf * 4 + q] = gw[q];
  __syncthreads();

  // ---- phase 2: 16x128x64 MFMA; wave w owns cols w*16..w*16+15 ----
  const int w = tid >> 6, lane = tid & 63;
  const int quad = lane >> 4, n16 = lane & 15;
  floatx4 acc4 = {0.f, 0.f, 0.f, 0.f};
#pragma unroll
  for (int kc = 0; kc < 4; ++kc) {
    const int kb = kc * 32 + quad * 8;
    const u32* ap = &lg[n16 * LG + (kb >> 1)];
    u32 aw[4] = {ap[0], ap[1], ap[2], ap[3]};
    short8 af = *(short8*)aw;
    short8 bf = ((const short8*)w2f)[(kc * 4 + w) * 64 + lane];
    acc4 = __builtin_amdgcn_mfma_f32_16x16x32_bf16(af, bf, acc4, 0, 0, 0);
  }
  float dd[4];
#pragma unroll
  for (int r4 = 0; r4 < 4; ++r4) {
    int rg = row0 + quad * 4 + r4;
    dd[r4] = (rg < N) ? dis[rg] : 0.f;
  }
#pragma unroll
  for (int r4 = 0; r4 < 4; ++r4)
    cb[(quad * 4 + r4) * LC + w * 16 + n16] = acc4[r4] * dd[r4];
  __syncthreads();

  // ---- int8 quantize h2 rows: 16 lanes per row, 4 cols each ----
  const int rr2 = tid >> 4, lf2 = tid & 15;
  const float* rp = cb + rr2 * LC + lf2 * 4;
  float mx = fmaxf(fmaxf(fabsf(rp[0]), fabsf(rp[1])),
                   fmaxf(fabsf(rp[2]), fabsf(rp[3])));
  mx = fmaxf(mx, __shfl_xor(mx, 1, 16));
  mx = fmaxf(mx, __shfl_xor(mx, 2, 16));
  mx = fmaxf(mx, __shfl_xor(mx, 4, 16));
  mx = fmaxf(mx, __shfl_xor(mx, 8, 16));
  const float inv2 = (mx > 0.f) ? 127.f / mx : 0.f;
  const int rg2 = row0 + rr2;
  if (rg2 < N) {
    u32 q0 = (u32)((int)rintf(rp[0] * inv2) + 128);
    u32 q1 = (u32)((int)rintf(rp[1] * inv2) + 128);
    u32 q2 = (u32)((int)rintf(rp[2] * inv2) + 128);
    u32 q3 = (u32)((int)rintf(rp[3] * inv2) + 128);
    h2[(long)rg2 * 16 + lf2] =
        (q0 & 255u) | ((q1 & 255u) << 8) | ((q2 & 255u) << 16) | (q3 << 24);
    if (lf2 == 0) s2[rg2] = mx / 127.f;
  }
}

// ---- dispatch 4: layer-2 gather (int8 h2, direct idx loads) + bias ----
__global__ __launch_bounds__(256) void k_gather2(
    const uint2* __restrict__ hs, const int* __restrict__ off,
    const int* __restrict__ deg, const ushort* __restrict__ csr,
    const float* __restrict__ dis, const float* __restrict__ sc2,
    const float* __restrict__ bias, float* __restrict__ out, int N) {
  constexpr int L = 8;  // lanes per node
  const int local = threadIdx.x / L;
  const int lf = threadIdx.x % L;
  const int n = blockIdx.x * (256 / L) + local;
  if (n >= N) return;
  const int s = off[n], e = s + deg[n];
  float acc[8] = {};
  float K = 0.f;
  {
    float t0 = sc2[n];
    dq8(acc, hs[(long)n * L + lf], t0);  // self-loop
    K += t0;
  }
  int j = s;
  for (; j + 8 <= e; j += 8) {
    us8 ev = *(const us8*)(csr + j);   // 16B aligned broadcast load
    const int i0 = ev[0], i1 = ev[1], i2 = ev[2], i3 = ev[3];
    const int i4 = ev[4], i5 = ev[5], i6 = ev[6], i7 = ev[7];
    const float d0 = sc2[i0], d1 = sc2[i1], d2 = sc2[i2], d3 = sc2[i3];
    const float d4 = sc2[i4], d5 = sc2[i5], d6 = sc2[i6], d7 = sc2[i7];
    uint2 v0 = hs[(long)i0 * L + lf];
    uint2 v1 = hs[(long)i1 * L + lf];
    uint2 v2 = hs[(long)i2 * L + lf];
    uint2 v3 = hs[(long)i3 * L + lf];
    uint2 v4 = hs[(long)i4 * L + lf];
    uint2 v5 = hs[(long)i5 * L + lf];
    uint2 v6 = hs[(long)i6 * L + lf];
    uint2 v7 = hs[(long)i7 * L + lf];
    dq8(acc, v0, d0); dq8(acc, v1, d1); dq8(acc, v2, d2); dq8(acc, v3, d3);
    dq8(acc, v4, d4); dq8(acc, v5, d5); dq8(acc, v6, d6); dq8(acc, v7, d7);
    K += ((d0 + d1) + (d2 + d3)) + ((d4 + d5) + (d6 + d7));
  }
  if (j < e) {
    us8 ev = *(const us8*)(csr + j);
#pragma unroll
    for (int t = 0; t < 8; ++t) {
      if (j + t < e) {
        const int it = ev[t];
        const float dt = sc2[it];
        dq8(acc, hs[(long)it * L + lf], dt);
        K += dt;
      }
    }
  }
  const float d = dis[n];
  const float kc = 128.f * K;
  const int f8 = lf * 8;
  const float4 b0 = *(const float4*)(bias + f8);
  const float4 b1v = *(const float4*)(bias + f8 + 4);
  float4 o0, o1;
  o0.x = (acc[0] - kc) * d + b0.x;
  o0.y = (acc[1] - kc) * d + b0.y;
  o0.z = (acc[2] - kc) * d + b0.z;
  o0.w = (acc[3] - kc) * d + b0.w;
  o1.x = (acc[4] - kc) * d + b1v.x;
  o1.y = (acc[5] - kc) * d + b1v.y;
  o1.z = (acc[6] - kc) * d + b1v.z;
  o1.w = (acc[7] - kc) * d + b1v.w;
  *(float4*)(out + (long)n * 64 + f8) = o0;
  *(float4*)(out + (long)n * 64 + f8 + 4) = o1;
}

extern "C" void kernel_launch(void* const* d_in, const int* in_sizes, int n_in,
                              void* d_out, int out_size, void* d_ws, size_t ws_size,
                              hipStream_t stream) {
  const float* x  = (const float*)d_in[0];
  const int*   ei = (const int*)d_in[1];   // [2,E] int32
  const float* W1 = (const float*)d_in[4];
  const float* b1 = (const float*)d_in[5];
  const float* W2 = (const float*)d_in[6];
  const float* b2 = (const float*)d_in[7];
  float* out = (float*)d_out;

  const int N = in_sizes[0] / 128;
  const int E = in_sizes[1] / 2;
  const int NBKT = cdiv_l(N, NPB);   // 98 (<=128; N<=65536 for 16-bit pack)
  const int NBE  = cdiv_l(E, EPB);   // 196
  const int G1   = cdiv_l(N, 64);    // 782 gemm1 blocks

  // workspace layout (4-byte elems):
  //   cur[128] | off[Np] | deg[Np] | dis[Np] | scale[Np] | sd[Np] | s2[Np]
  //   | w1f[8192] | w2f[4096] | ebuf[BW u32] | csr[BW ushort]
  //   | h8[N*32 u32] | h2[N*16 u32]
  const long Np = (N + 64) & ~63L;
  const long BW = (long)NBKT * CAP;
  int*    cur   = (int*)d_ws;
  int*    off   = cur + 128;
  int*    deg   = off + Np;
  float*  dis   = (float*)(deg + Np);
  float*  scale = dis + Np;
  float*  sd    = scale + Np;
  float*  s2    = sd + Np;
  u32*    w1f   = (u32*)(s2 + Np);       // 2048 slots * 4 u32 = 32 KB
  u32*    w2f   = w1f + 8192;            // 1024 slots * 4 u32 = 16 KB
  u32*    ebuf  = w2f + 4096;
  ushort* csr   = (ushort*)(ebuf + BW);
  u32*    h8    = (u32*)(csr + BW);      // BW ushorts = BW/2 u32 words
  u32*    h2    = h8 + (long)N * 32;

  // ---- cursors -> 0 + W1/W2 fragment-pack ----
  k_pack<<<12, 256, 0, stream>>>(W1, W2, w1f, w2f, cur);

  // ---- fused: edge partition (blocks 0..NBE) || GEMM1+int8 (blocks NBE..) ----
  k_fused1<<<NBE + G1, 256, 0, stream>>>(ei, cur, ebuf, E, NBE, x, w1f, h8,
                                         scale, N);

  // ---- per-bucket CSR finalize (+ sd fold, 8-aligned starts) ----
  k_csr<<<NBKT, 1024, 0, stream>>>(ebuf, cur, scale, off, deg, dis, sd, csr, N);

  // ---- gather1 (int8) + relu + GEMM2 fused + h2 int8 quantize ----
  k_gg<<<cdiv_l(N, 16), 256, 0, stream>>>((const uint2*)h8, off, deg, csr,
                                          dis, sd, b1, w2f, h2, s2, N);

  // ---- layer-2 gather (int8) + bias ----
  k_gather2<<<cdiv_l(N, 32), 256, 0, stream>>>((const uint2*)h2, off, deg, csr,
                                               dis, s2, b2, out, N);
}

// Round 9
// 146.235 us; speedup vs baseline: 1.1440x; 1.0219x over previous
//
#include <hip/hip_runtime.h>

// GCN link-prediction forward: 2× GCNConv (128->128 relu, 128->64) on
// N=50000 nodes, E=800000 random edges. fp32 compute, int8 messages.
//
// Algebra: with dis[n] = rsqrt(indeg[n]+1),
//   conv(x)[c] = ( sum_{r->c} h[r]*dis[r] + h[c]*dis[c] ) * dis[c] + b,
//   h = x@W (unscaled). Messages stored int8 (per-row scale, biased +128;
//   exact -128 correction via K = sum of scales).
//
// R2..R9: 2737 -> 169 us (CSR gather, MFMA, fusion, bucketed sort).
// R10: src-sorted gather: +1% -- locality falsified.
// R11: layer-1 messages int8 (169 -> 161 us).
// R12/R14: layer-2 int8; gather2 LATENCY-bound, not traffic-bound.
// R15: W1/W2 pre-packed bf16 fragment-major (k_pack): 158.8.
// R16: gathers de-shuffled (direct 16B ushort8 idx loads, 8-padded CSR
//      starts): 152.1 us.
// R17: cooperative fusion: 301 us (grid.sync ~80-100us/sync). REVERTED.
//      Key datum: k_gg + k_gather2 + boundaries ~6-8 us total.
// R18: dummy-pad + x2 unroll gathers: +4. REVERTED.
// R19: sub-window partition + self-converted W1: +15. REVERTED.
// R20: in-block W1->LDS conversion: +9.7. REVERTED.
//      Lesson x3: never trade dispatch count for per-block work.
// R21: k_csr 1024 threads + LDS edge cache: 149.4 us. BEST.
//      Targeted latency/occupancy fixes win; structural rewires lose.
// R22: k_csr CU coverage 2x: NPB 512->256 (196 buckets/blocks, 77% of
//      CUs vs 38%), per-thread chain 8->4 edges/pass, CAP 8192
//      (mean 4082 + 5sigma 320 + pad<=1792 = 6194). Partition hist
//      c>>8, 8-bit local node. Everything else byte-identical to R21.

typedef unsigned int u32;
typedef unsigned short ushort;
typedef __attribute__((ext_vector_type(8))) short short8;
typedef __attribute__((ext_vector_type(8))) unsigned short us8;
typedef __attribute__((ext_vector_type(4))) float floatx4;

static inline int cdiv_l(long a, int b) { return (int)((a + b - 1) / b); }

constexpr int NPB  = 256;    // nodes per bucket (2^8)
constexpr int EPB  = 4096;   // edges per partition block
constexpr int MAXB = 256;    // max buckets (N <= 65536)
constexpr int CAP  = 8192;   // per-bucket edge capacity
// mean 4082, +5sigma ~320, +8-pad overhead <=1792 -> worst ~6194 < 8192.

__device__ __forceinline__ u32 pack_bf16(float a, float b) {
  union { float f; u32 i; } ua, ub;
  ua.f = a; ub.f = b;
  u32 x = (ua.i + 0x7fffu + ((ua.i >> 16) & 1u)) >> 16;           // rne, low
  u32 y = (ub.i + 0x7fffu + ((ub.i >> 16) & 1u)) & 0xffff0000u;   // rne, high
  return x | y;
}

__device__ __forceinline__ short bf16r(float f) {
  union { float f; u32 i; } u; u.f = f;
  return (short)((u.i + 0x7fffu + ((u.i >> 16) & 1u)) >> 16);     // rne
}

// int8 dequant-accumulate: 8 biased uint8 -> acc += (float)q * sd
// (the -128 bias is corrected once per node via K = sum of sd).
__device__ __forceinline__ void dq8(float* a, uint2 v, float sd) {
  a[0] += (float)(v.x & 255u) * sd;
  a[1] += (float)((v.x >> 8) & 255u) * sd;
  a[2] += (float)((v.x >> 16) & 255u) * sd;
  a[3] += (float)(v.x >> 24) * sd;
  a[4] += (float)(v.y & 255u) * sd;
  a[5] += (float)((v.y >> 8) & 255u) * sd;
  a[6] += (float)((v.y >> 16) & 255u) * sd;
  a[7] += (float)(v.y >> 24) * sd;
}

// ---- dispatch 0: zero cursors + pack W1/W2 into MFMA B-fragment bf16 ----
// Fragment layout: slot s = frag*64 + lane; frag = kc*(M/16) + cb.
// Lane's short8: elem j = bf16(W[(kc*32 + (lane>>4)*8 + j)*M + cb*16 + (lane&15)])
// so GEMM B-load is ONE coalesced 16B read, zero conversion VALU.
__global__ __launch_bounds__(256) void k_pack(
    const float* __restrict__ W1, const float* __restrict__ W2,
    u32* __restrict__ w1f, u32* __restrict__ w2f, int* __restrict__ cur) {
  const int tid = threadIdx.x;
  const int b = blockIdx.x;
  if (b == 0 && tid < MAXB) cur[tid] = 0;
  if (b < 8) {
    // W1: 128x128 -> 2048 slots (8 blocks x 256)
    const int s = b * 256 + tid;
    const int lane = s & 63, frag = s >> 6;
    const int kc = frag >> 3, cb = frag & 7;
    const float* src =
        W1 + (long)(kc * 32 + (lane >> 4) * 8) * 128 + cb * 16 + (lane & 15);
    u32 o[4];
#pragma unroll
    for (int p = 0; p < 4; ++p)
      o[p] = pack_bf16(src[(2 * p) * 128], src[(2 * p + 1) * 128]);
    *(uint4*)(w1f + (long)s * 4) = make_uint4(o[0], o[1], o[2], o[3]);
  } else {
    // W2: 128x64 -> 1024 slots (4 blocks x 256)
    const int s = (b - 8) * 256 + tid;
    const int lane = s & 63, frag = s >> 6;
    const int kc = frag >> 2, cb = frag & 3;
    const float* src =
        W2 + (long)(kc * 32 + (lane >> 4) * 8) * 64 + cb * 16 + (lane & 15);
    u32 o[4];
#pragma unroll
    for (int p = 0; p < 4; ++p)
      o[p] = pack_bf16(src[(2 * p) * 64], src[(2 * p + 1) * 64]);
    *(uint4*)(w2f + (long)s * 4) = make_uint4(o[0], o[1], o[2], o[3]);
  }
}

// ---- fused dispatch 1: blocks [0,NBE) partition edges into bucket windows;
// ---- blocks [NBE,..) compute h8 = int8(x@W1) + per-row scale (no dis).
__global__ __launch_bounds__(256) void k_fused1(
    const int* __restrict__ ei, int* __restrict__ cur, u32* __restrict__ ebuf,
    int E, int NBE,
    const float* __restrict__ x, const u32* __restrict__ w1f,
    u32* __restrict__ h8, float* __restrict__ scale, int N) {
  __shared__ float eb[4][16 * 133];   // gemm epilogue staging (34 KB)
  const int tid = threadIdx.x;

  if (blockIdx.x < (unsigned)NBE) {
    // ===== edge partition (counting sort pass 1), LDS edge cache =====
    u32* ecache = (u32*)&eb[0][0];          // 4096 u32 = 16 KB (in eb[0..1])
    int* hist   = (int*)&eb[2][0];          // MAXB ints (in eb[2])
    int* curs   = hist + MAXB;
    const int* ecol = ei + E;
    if (tid < MAXB) hist[tid] = 0;
    __syncthreads();
    const int base = blockIdx.x * EPB;
#pragma unroll
    for (int j = 0; j < EPB / 256; ++j) {
      int e = base + j * 256 + tid;
      u32 pk = 0xffffffffu;
      if (e < E) {
        u32 r = (u32)ei[e];
        u32 c = (u32)ecol[e];
        pk = r | (c << 16);
        atomicAdd(hist + (c >> 8), 1);
      }
      ecache[j * 256 + tid] = pk;
    }
    __syncthreads();
    if (tid < MAXB) {
      int n = hist[tid];
      curs[tid] = tid * CAP + (n ? atomicAdd(cur + tid, n) : 0);
    }
    __syncthreads();
#pragma unroll
    for (int j = 0; j < EPB / 256; ++j) {
      u32 pk = ecache[j * 256 + tid];
      if (pk != 0xffffffffu) {
        u32 c = pk >> 16;
        int b = c >> 8;
        int p = atomicAdd(curs + b, 1);
        if (p < (b + 1) * CAP)  // overflow guard (statistically impossible)
          ebuf[p] = (pk & 0xffffu) | ((c & (NPB - 1)) << 16);
      }
    }
    return;
  }

  // ===== MFMA GEMM1: h8[row,:] = int8(x[row,:] @ W1), K=M=128 =====
  constexpr int K = 128, NC = 8, LROW = 133;
  const int w = tid >> 6, lane = tid & 63;
  const int quad = lane >> 4, n16 = lane & 15;
  const int row0 = ((blockIdx.x - NBE) * 4 + w) * 16;

  floatx4 acc[NC];
#pragma unroll
  for (int c = 0; c < NC; ++c) acc[c] = {0.f, 0.f, 0.f, 0.f};

  const int am = row0 + n16;
  const bool av = am < N;
  const float* arow = x + (long)am * K;
  const short8* wf = (const short8*)w1f;

#pragma unroll
  for (int kc = 0; kc < 4; ++kc) {
    const int kb = kc * 32 + quad * 8;
    float4 a0 = make_float4(0.f, 0.f, 0.f, 0.f);
    float4 a1 = make_float4(0.f, 0.f, 0.f, 0.f);
    if (av) {
      a0 = *(const float4*)(arow + kb);
      a1 = *(const float4*)(arow + kb + 4);
    }
    short8 af;
    af[0] = bf16r(a0.x); af[1] = bf16r(a0.y); af[2] = bf16r(a0.z); af[3] = bf16r(a0.w);
    af[4] = bf16r(a1.x); af[5] = bf16r(a1.y); af[6] = bf16r(a1.z); af[7] = bf16r(a1.w);
#pragma unroll
    for (int c = 0; c < NC; ++c) {
      short8 bf = wf[(kc * 8 + c) * 64 + lane];
      acc[c] = __builtin_amdgcn_mfma_f32_16x16x32_bf16(af, bf, acc[c], 0, 0, 0);
    }
  }

  float* ep = eb[w];
#pragma unroll
  for (int c = 0; c < NC; ++c)
#pragma unroll
    for (int r = 0; r < 4; ++r)
      ep[(quad * 4 + r) * LROW + c * 16 + n16] = acc[c][r];
  __syncthreads();

  // int8 quantize: lane -> row rr = lane>>2, col segment seg*32..+31
  const int rr = lane >> 2, seg = lane & 3;
  const float* rowp = ep + rr * LROW + seg * 32;
  float m = 0.f;
#pragma unroll
  for (int c = 0; c < 32; ++c) m = fmaxf(m, fabsf(rowp[c]));
  m = fmaxf(m, __shfl_xor(m, 1, 4));
  m = fmaxf(m, __shfl_xor(m, 2, 4));
  const float inv = (m > 0.f) ? 127.f / m : 0.f;
  const float s = m / 127.f;
  u32 q[8];
#pragma unroll
  for (int wd = 0; wd < 8; ++wd) {
    u32 b0 = (u32)((int)rintf(rowp[wd * 4 + 0] * inv) + 128);
    u32 b1 = (u32)((int)rintf(rowp[wd * 4 + 1] * inv) + 128);
    u32 b2 = (u32)((int)rintf(rowp[wd * 4 + 2] * inv) + 128);
    u32 b3 = (u32)((int)rintf(rowp[wd * 4 + 3] * inv) + 128);
    q[wd] = (b0 & 255u) | ((b1 & 255u) << 8) | ((b2 & 255u) << 16) | (b3 << 24);
  }
  const int rg = row0 + rr;
  if (rg < N) {
    uint4* dst = (uint4*)(h8 + (long)rg * 32 + seg * 8);
    dst[0] = make_uint4(q[0], q[1], q[2], q[3]);
    dst[1] = make_uint4(q[4], q[5], q[6], q[7]);
    if (seg == 0) scale[rg] = s;
  }
}

// ---- dispatch 2: per-bucket CSR finalize + sd fold; starts padded to 8.
// ---- 1024 threads, LDS edge cache, 196 blocks (NPB=256). ----
__global__ __launch_bounds__(1024) void k_csr(const u32* __restrict__ ebuf,
                                              const int* __restrict__ cur,
                                              const float* __restrict__ scale,
                                              int* __restrict__ off,
                                              int* __restrict__ deg,
                                              float* __restrict__ dis,
                                              float* __restrict__ sd,
                                              ushort* __restrict__ csr, int N) {
  __shared__ u32 ecache[CAP];     // 32 KB edge cache
  __shared__ int cnt[NPB];
  __shared__ int curl[NPB];
  __shared__ int wsum[NPB / 64];
  const int tid = threadIdx.x;
  const int b = blockIdx.x;
  const int s = b * CAP;
  const int e = s + min(cur[b], CAP);
  if (tid < NPB) cnt[tid] = 0;
  __syncthreads();
  for (int i = s + tid; i < e; i += 1024) {
    u32 pk = ebuf[i];
    ecache[i - s] = pk;
    atomicAdd(cnt + (pk >> 16), 1);
  }
  __syncthreads();
  const int lane = tid & 63, w = tid >> 6;
  int v = 0, vp = 0, incl = 0;
  if (tid < NPB) {                 // waves 0..3 (uniform per wave)
    v = cnt[tid];
    vp = (v + 7) & ~7;             // padded length (8-aligned starts)
    incl = vp;
#pragma unroll
    for (int d = 1; d < 64; d <<= 1) {
      int x = __shfl_up(incl, d, 64);
      if (lane >= d) incl += x;
    }
    if (lane == 63) wsum[w] = incl;
  }
  __syncthreads();
  if (w == 0 && lane < NPB / 64) {
    int sv = wsum[lane];
#pragma unroll
    for (int d = 1; d < NPB / 64; d <<= 1) {
      int x = __shfl_up(sv, d, 64);
      if (lane >= d) sv += x;
    }
    wsum[lane] = sv;
  }
  __syncthreads();
  if (tid < NPB) {
    const int excl = ((w > 0) ? wsum[w - 1] : 0) + incl - vp;
    const int node = b * NPB + tid;
    if (node < N) {
      float dv = rsqrtf((float)v + 1.0f);
      off[node] = s + excl;
      deg[node] = v;
      dis[node] = dv;
      sd[node] = scale[node] * dv;
    }
    curl[tid] = excl;
  }
  __syncthreads();
  for (int i = s + tid; i < e; i += 1024) {
    u32 pk = ecache[i - s];
    int p = atomicAdd(curl + (pk >> 16), 1);
    csr[s + p] = (ushort)(pk & 0xffffu);
  }
}

// ---- dispatch 3: fused gather1 (int8 msgs, direct idx loads) + relu +
// ---- GEMM2; epilogue quantizes h2 to int8 (per-row scale s2). ----
__global__ __launch_bounds__(256) void k_gg(
    const uint2* __restrict__ h8, const int* __restrict__ off,
    const int* __restrict__ deg, const ushort* __restrict__ csr,
    const float* __restrict__ dis, const float* __restrict__ sd,
    const float* __restrict__ b1, const u32* __restrict__ w2f,
    u32* __restrict__ h2, float* __restrict__ s2, int N) {
  constexpr int LG = 65;   // u32 words per g row (64 + pad)
  constexpr int LC = 66;   // f32 words per C row (64 + pad)
  __shared__ u32 lg[16 * LG];
  __shared__ float cb[16 * LC];
  const int tid = threadIdx.x;
  const int r = tid >> 4;          // local node 0..15
  const int lf = tid & 15;         // lane within 16-group (8-byte chunk)
  const int row0 = blockIdx.x * 16;
  const int n = row0 + r;

  // ---- phase 1: int8 gather (rows = 128B = 2 lines) ----
  u32 gw[4] = {0, 0, 0, 0};
  if (n < N) {
    const int s = off[n], e = s + deg[n];
    const float dn = dis[n];
    float acc[8] = {};
    float K = 0.f;
    {
      float sn = sd[n];
      dq8(acc, h8[(long)n * 16 + lf], sn);  // self-loop
      K += sn;
    }
    int j = s;
    for (; j + 8 <= e; j += 8) {
      us8 ev = *(const us8*)(csr + j);   // 16B aligned broadcast load
      const int i0 = ev[0], i1 = ev[1], i2 = ev[2], i3 = ev[3];
      const int i4 = ev[4], i5 = ev[5], i6 = ev[6], i7 = ev[7];
      const float d0 = sd[i0], d1 = sd[i1], d2 = sd[i2], d3 = sd[i3];
      const float d4 = sd[i4], d5 = sd[i5], d6 = sd[i6], d7 = sd[i7];
      uint2 v0 = h8[(long)i0 * 16 + lf];
      uint2 v1 = h8[(long)i1 * 16 + lf];
      uint2 v2 = h8[(long)i2 * 16 + lf];
      uint2 v3 = h8[(long)i3 * 16 + lf];
      uint2 v4 = h8[(long)i4 * 16 + lf];
      uint2 v5 = h8[(long)i5 * 16 + lf];
      uint2 v6 = h8[(long)i6 * 16 + lf];
      uint2 v7 = h8[(long)i7 * 16 + lf];
      dq8(acc, v0, d0); dq8(acc, v1, d1); dq8(acc, v2, d2); dq8(acc, v3, d3);
      dq8(acc, v4, d4); dq8(acc, v5, d5); dq8(acc, v6, d6); dq8(acc, v7, d7);
      K += ((d0 + d1) + (d2 + d3)) + ((d4 + d5) + (d6 + d7));
    }
    if (j < e) {
      us8 ev = *(const us8*)(csr + j);
#pragma unroll
      for (int t = 0; t < 8; ++t) {
        if (j + t < e) {
          const int it = ev[t];
          const float dt = sd[it];
          dq8(acc, h8[(long)it * 16 + lf], dt);
          K += dt;
        }
      }
    }
    const int f8 = lf * 8;
    const float4 bv0 = *(const float4*)(b1 + f8);
    const float4 bv1 = *(const float4*)(b1 + f8 + 4);
    const float bb[8] = {bv0.x, bv0.y, bv0.z, bv0.w, bv1.x, bv1.y, bv1.z, bv1.w};
    const float kc = 128.f * K;
#pragma unroll
    for (int q = 0; q < 8; ++q)
      acc[q] = fmaxf((acc[q] - kc) * dn + bb[q], 0.f);
#pragma unroll
    for (int q = 0; q < 4; ++q)
      gw[q] = pack_bf16(acc[2 * q], acc[2 * q + 1]);
  }
#pragma unroll
  for (int q = 0; q < 4; ++q) lg[r * LG + lf * 4 + q] = gw[q];
  __syncthreads();

  // ---- phase 2: 16x128x64 MFMA; wave w owns cols w*16..w*16+15 ----
  const int w = tid >> 6, lane = tid & 63;
  const int quad = lane >> 4, n16 = lane & 15;
  floatx4 acc4 = {0.f, 0.f, 0.f, 0.f};
#pragma unroll
  for (int kc = 0; kc < 4; ++kc) {
    const int kb = kc * 32 + quad * 8;
    const u32* ap = &lg[n16 * LG + (kb >> 1)];
    u32 aw[4] = {ap[0], ap[1], ap[2], ap[3]};
    short8 af = *(short8*)aw;
    short8 bf = ((const short8*)w2f)[(kc * 4 + w) * 64 + lane];
    acc4 = __builtin_amdgcn_mfma_f32_16x16x32_bf16(af, bf, acc4, 0, 0, 0);
  }
  float dd[4];
#pragma unroll
  for (int r4 = 0; r4 < 4; ++r4) {
    int rg = row0 + quad * 4 + r4;
    dd[r4] = (rg < N) ? dis[rg] : 0.f;
  }
#pragma unroll
  for (int r4 = 0; r4 < 4; ++r4)
    cb[(quad * 4 + r4) * LC + w * 16 + n16] = acc4[r4] * dd[r4];
  __syncthreads();

  // ---- int8 quantize h2 rows: 16 lanes per row, 4 cols each ----
  const int rr2 = tid >> 4, lf2 = tid & 15;
  const float* rp = cb + rr2 * LC + lf2 * 4;
  float mx = fmaxf(fmaxf(fabsf(rp[0]), fabsf(rp[1])),
                   fmaxf(fabsf(rp[2]), fabsf(rp[3])));
  mx = fmaxf(mx, __shfl_xor(mx, 1, 16));
  mx = fmaxf(mx, __shfl_xor(mx, 2, 16));
  mx = fmaxf(mx, __shfl_xor(mx, 4, 16));
  mx = fmaxf(mx, __shfl_xor(mx, 8, 16));
  const float inv2 = (mx > 0.f) ? 127.f / mx : 0.f;
  const int rg2 = row0 + rr2;
  if (rg2 < N) {
    u32 q0 = (u32)((int)rintf(rp[0] * inv2) + 128);
    u32 q1 = (u32)((int)rintf(rp[1] * inv2) + 128);
    u32 q2 = (u32)((int)rintf(rp[2] * inv2) + 128);
    u32 q3 = (u32)((int)rintf(rp[3] * inv2) + 128);
    h2[(long)rg2 * 16 + lf2] =
        (q0 & 255u) | ((q1 & 255u) << 8) | ((q2 & 255u) << 16) | (q3 << 24);
    if (lf2 == 0) s2[rg2] = mx / 127.f;
  }
}

// ---- dispatch 4: layer-2 gather (int8 h2, direct idx loads) + bias ----
__global__ __launch_bounds__(256) void k_gather2(
    const uint2* __restrict__ hs, const int* __restrict__ off,
    const int* __restrict__ deg, const ushort* __restrict__ csr,
    const float* __restrict__ dis, const float* __restrict__ sc2,
    const float* __restrict__ bias, float* __restrict__ out, int N) {
  constexpr int L = 8;  // lanes per node
  const int local = threadIdx.x / L;
  const int lf = threadIdx.x % L;
  const int n = blockIdx.x * (256 / L) + local;
  if (n >= N) return;
  const int s = off[n], e = s + deg[n];
  float acc[8] = {};
  float K = 0.f;
  {
    float t0 = sc2[n];
    dq8(acc, hs[(long)n * L + lf], t0);  // self-loop
    K += t0;
  }
  int j = s;
  for (; j + 8 <= e; j += 8) {
    us8 ev = *(const us8*)(csr + j);   // 16B aligned broadcast load
    const int i0 = ev[0], i1 = ev[1], i2 = ev[2], i3 = ev[3];
    const int i4 = ev[4], i5 = ev[5], i6 = ev[6], i7 = ev[7];
    const float d0 = sc2[i0], d1 = sc2[i1], d2 = sc2[i2], d3 = sc2[i3];
    const float d4 = sc2[i4], d5 = sc2[i5], d6 = sc2[i6], d7 = sc2[i7];
    uint2 v0 = hs[(long)i0 * L + lf];
    uint2 v1 = hs[(long)i1 * L + lf];
    uint2 v2 = hs[(long)i2 * L + lf];
    uint2 v3 = hs[(long)i3 * L + lf];
    uint2 v4 = hs[(long)i4 * L + lf];
    uint2 v5 = hs[(long)i5 * L + lf];
    uint2 v6 = hs[(long)i6 * L + lf];
    uint2 v7 = hs[(long)i7 * L + lf];
    dq8(acc, v0, d0); dq8(acc, v1, d1); dq8(acc, v2, d2); dq8(acc, v3, d3);
    dq8(acc, v4, d4); dq8(acc, v5, d5); dq8(acc, v6, d6); dq8(acc, v7, d7);
    K += ((d0 + d1) + (d2 + d3)) + ((d4 + d5) + (d6 + d7));
  }
  if (j < e) {
    us8 ev = *(const us8*)(csr + j);
#pragma unroll
    for (int t = 0; t < 8; ++t) {
      if (j + t < e) {
        const int it = ev[t];
        const float dt = sc2[it];
        dq8(acc, hs[(long)it * L + lf], dt);
        K += dt;
      }
    }
  }
  const float d = dis[n];
  const float kc = 128.f * K;
  const int f8 = lf * 8;
  const float4 b0 = *(const float4*)(bias + f8);
  const float4 b1v = *(const float4*)(bias + f8 + 4);
  float4 o0, o1;
  o0.x = (acc[0] - kc) * d + b0.x;
  o0.y = (acc[1] - kc) * d + b0.y;
  o0.z = (acc[2] - kc) * d + b0.z;
  o0.w = (acc[3] - kc) * d + b0.w;
  o1.x = (acc[4] - kc) * d + b1v.x;
  o1.y = (acc[5] - kc) * d + b1v.y;
  o1.z = (acc[6] - kc) * d + b1v.z;
  o1.w = (acc[7] - kc) * d + b1v.w;
  *(float4*)(out + (long)n * 64 + f8) = o0;
  *(float4*)(out + (long)n * 64 + f8 + 4) = o1;
}

extern "C" void kernel_launch(void* const* d_in, const int* in_sizes, int n_in,
                              void* d_out, int out_size, void* d_ws, size_t ws_size,
                              hipStream_t stream) {
  const float* x  = (const float*)d_in[0];
  const int*   ei = (const int*)d_in[1];   // [2,E] int32
  const float* W1 = (const float*)d_in[4];
  const float* b1 = (const float*)d_in[5];
  const float* W2 = (const float*)d_in[6];
  const float* b2 = (const float*)d_in[7];
  float* out = (float*)d_out;

  const int N = in_sizes[0] / 128;
  const int E = in_sizes[1] / 2;
  const int NBKT = cdiv_l(N, NPB);   // 196 (<=256; N<=65536 for 16-bit pack)
  const int NBE  = cdiv_l(E, EPB);   // 196
  const int G1   = cdiv_l(N, 64);    // 782 gemm1 blocks

  // workspace layout (4-byte elems):
  //   cur[256] | off[Np] | deg[Np] | dis[Np] | scale[Np] | sd[Np] | s2[Np]
  //   | w1f[8192] | w2f[4096] | ebuf[BW u32] | csr[BW ushort]
  //   | h8[N*32 u32] | h2[N*16 u32]
  const long Np = (N + 64) & ~63L;
  const long BW = (long)NBKT * CAP;
  int*    cur   = (int*)d_ws;
  int*    off   = cur + 256;
  int*    deg   = off + Np;
  float*  dis   = (float*)(deg + Np);
  float*  scale = dis + Np;
  float*  sd    = scale + Np;
  float*  s2    = sd + Np;
  u32*    w1f   = (u32*)(s2 + Np);       // 2048 slots * 4 u32 = 32 KB
  u32*    w2f   = w1f + 8192;            // 1024 slots * 4 u32 = 16 KB
  u32*    ebuf  = w2f + 4096;
  ushort* csr   = (ushort*)(ebuf + BW);
  u32*    h8    = (u32*)(csr + BW);      // BW ushorts = BW/2 u32 words
  u32*    h2    = h8 + (long)N * 32;

  // ---- cursors -> 0 + W1/W2 fragment-pack ----
  k_pack<<<12, 256, 0, stream>>>(W1, W2, w1f, w2f, cur);

  // ---- fused: edge partition (blocks 0..NBE) || GEMM1+int8 (blocks NBE..) ----
  k_fused1<<<NBE + G1, 256, 0, stream>>>(ei, cur, ebuf, E, NBE, x, w1f, h8,
                                         scale, N);

  // ---- per-bucket CSR finalize (+ sd fold, 8-aligned starts) ----
  k_csr<<<NBKT, 1024, 0, stream>>>(ebuf, cur, scale, off, deg, dis, sd, csr, N);

  // ---- gather1 (int8) + relu + GEMM2 fused + h2 int8 quantize ----
  k_gg<<<cdiv_l(N, 16), 256, 0, stream>>>((const uint2*)h8, off, deg, csr,
                                          dis, sd, b1, w2f, h2, s2, N);

  // ---- layer-2 gather (int8) + bias ----
  k_gather2<<<cdiv_l(N, 32), 256, 0, stream>>>((const uint2*)h2, off, deg, csr,
                                               dis, s2, b2, out, N);
}